// Round 1
// baseline (570.421 us; speedup 1.0000x reference)
//
#include <hip/hip_runtime.h>
#include <stdint.h>
#include <stddef.h>

typedef unsigned short u16;
typedef float  f32x4  __attribute__((ext_vector_type(4)));
typedef short  s16x8  __attribute__((ext_vector_type(8)));
typedef __bf16 bf16x8 __attribute__((ext_vector_type(8)));
typedef u16    u16x4  __attribute__((ext_vector_type(4)));

#define DEV static __device__ __forceinline__

DEV u16 f2bf(float f){
  uint32_t u = __builtin_bit_cast(uint32_t, f);
  u += 0x7FFFu + ((u >> 16) & 1u);   // round-to-nearest-even
  return (u16)(u >> 16);
}

DEV f32x4 mfma16(s16x8 a, s16x8 b, f32x4 c){
  return __builtin_amdgcn_mfma_f32_16x16x32_bf16(
      __builtin_bit_cast(bf16x8, a), __builtin_bit_cast(bf16x8, b), c, 0, 0, 0);
}

DEV void gl_lds16(const u16* g, u16* l){
  __builtin_amdgcn_global_load_lds(
      (__attribute__((address_space(1))) void*)(g),
      (__attribute__((address_space(3))) void*)(l), 16, 0, 0);
}

// ---------------- fp32 -> bf16 convert ----------------
__global__ __launch_bounds__(256) void cvt_f2b(const float* __restrict__ in,
                                               u16* __restrict__ out, int n4){
  int stride = gridDim.x * blockDim.x;
  for (int i = blockIdx.x * blockDim.x + threadIdx.x; i < n4; i += stride){
    float4 v = *(const float4*)(in + (size_t)i * 4);
    u16x4 o = { f2bf(v.x), f2bf(v.y), f2bf(v.z), f2bf(v.w) };
    *(u16x4*)(out + (size_t)i * 4) = o;
  }
}

// ---------------- 128x128 bf16 GEMM core: C = A * Bw^T ----------------
// A: M x K row-major.  Bw: N x K row-major.  K % 64 == 0. 256 threads (4 waves 2x2).
DEV void gemm_core(const u16* __restrict__ A, const u16* __restrict__ Bw,
                   int K, int bm, int bn, u16* ldsA, u16* ldsB, f32x4 acc[4][4])
{
  const int lane = threadIdx.x & 63;
  const int wave = threadIdx.x >> 6;
  const int wm = (wave >> 1) * 64, wn = (wave & 1) * 64;
  const int l8 = (lane & 7) * 8;   // staging k-offset (elements)
  const int lr = lane >> 3;        // staging row within 8-row chunk
  const int fr = lane & 15;
  const int k8 = (lane >> 4) * 8;

  #pragma unroll
  for (int m = 0; m < 4; m++)
    #pragma unroll
    for (int n = 0; n < 4; n++){ f32x4 z = {0.f,0.f,0.f,0.f}; acc[m][n] = z; }

  const int nkt = K >> 6;
  for (int kt = 0; kt < nkt; ++kt){
    const int kb = kt * 64;
    #pragma unroll
    for (int i = 0; i < 4; i++){
      const int c   = wave * 4 + i;   // chunk 0..15, 1 KiB each (8 rows x 128 B)
      const int row = c * 8 + lr;
      gl_lds16(A  + (size_t)(bm + row) * K + kb + l8, ldsA + c * 512);
      gl_lds16(Bw + (size_t)(bn + row) * K + kb + l8, ldsB + c * 512);
    }
    __syncthreads();
    #pragma unroll
    for (int kk = 0; kk < 2; ++kk){
      s16x8 af[4], bfr[4];
      #pragma unroll
      for (int m = 0; m < 4; m++) af[m]  = *(const s16x8*)(ldsA + (wm + m*16 + fr)*64 + kk*32 + k8);
      #pragma unroll
      for (int n = 0; n < 4; n++) bfr[n] = *(const s16x8*)(ldsB + (wn + n*16 + fr)*64 + kk*32 + k8);
      #pragma unroll
      for (int m = 0; m < 4; m++)
        #pragma unroll
        for (int n = 0; n < 4; n++)
          acc[m][n] = mfma16(af[m], bfr[n], acc[m][n]);
    }
    __syncthreads();
  }
}

// ---------------- QKV projection: C scattered to Q, K, Vt (bf16) ----------------
// x: 8192x1024, w: 3072x1024 (rows = (q,h,dk)). Q,K: (b,h,s,dk). Vt: (b,h,dk,s). Q pre-scaled.
__global__ __launch_bounds__(256) void gemm_qkv(const u16* __restrict__ xb,
                                                const u16* __restrict__ wb,
                                                u16* __restrict__ Qd,
                                                u16* __restrict__ Kd,
                                                u16* __restrict__ Vtd)
{
  __shared__ __align__(16) u16 ldsA[128*64];
  __shared__ __align__(16) u16 ldsB[128*64];
  f32x4 acc[4][4];
  const int bm = blockIdx.x * 128, bn = blockIdx.y * 128;
  gemm_core(xb, wb, 1024, bm, bn, ldsA, ldsB, acc);

  const int lane = threadIdx.x & 63, wave = threadIdx.x >> 6;
  const int wm = (wave >> 1) * 64, wn = (wave & 1) * 64;
  const int fr = lane & 15, r4 = (lane >> 4) * 4;
  const int q = bn >> 10;   // uniform per block (128 | 1024)

  #pragma unroll
  for (int m = 0; m < 4; m++){
    const int i0 = bm + wm + m*16 + r4;       // 4 consecutive rows (b,s)
    const int b  = i0 >> 11;
    const int s0 = i0 & 2047;
    #pragma unroll
    for (int n = 0; n < 4; n++){
      const int ng = bn + wn + n*16 + fr;
      const int h  = (ng >> 6) & 15, kd = ng & 63;
      const size_t bh = (size_t)(b * 16 + h);
      if (q == 0){
        #pragma unroll
        for (int r = 0; r < 4; r++)
          Qd[(bh*2048 + s0 + r)*64 + kd] = f2bf(acc[m][n][r] * 0.125f);
      } else if (q == 1){
        #pragma unroll
        for (int r = 0; r < 4; r++)
          Kd[(bh*2048 + s0 + r)*64 + kd] = f2bf(acc[m][n][r]);
      } else {
        u16x4 v = { f2bf(acc[m][n][0]), f2bf(acc[m][n][1]),
                    f2bf(acc[m][n][2]), f2bf(acc[m][n][3]) };
        *(u16x4*)(Vtd + (bh*64 + kd)*2048 + s0) = v;   // transposed: 4 consecutive s
      }
    }
  }
}

// ---------------- out projection: fp32 C ----------------
__global__ __launch_bounds__(256) void gemm_outp(const u16* __restrict__ attnb,
                                                 const u16* __restrict__ wob,
                                                 float* __restrict__ C)
{
  __shared__ __align__(16) u16 ldsA[128*64];
  __shared__ __align__(16) u16 ldsB[128*64];
  f32x4 acc[4][4];
  const int bm = blockIdx.x * 128, bn = blockIdx.y * 128;
  gemm_core(attnb, wob, 1024, bm, bn, ldsA, ldsB, acc);

  const int lane = threadIdx.x & 63, wave = threadIdx.x >> 6;
  const int wm = (wave >> 1) * 64, wn = (wave & 1) * 64;
  const int fr = lane & 15, r4 = (lane >> 4) * 4;
  #pragma unroll
  for (int m = 0; m < 4; m++){
    const int i0 = bm + wm + m*16 + r4;
    #pragma unroll
    for (int n = 0; n < 4; n++){
      const int ng = bn + wn + n*16 + fr;
      #pragma unroll
      for (int r = 0; r < 4; r++)
        C[(size_t)(i0 + r) * 1024 + ng] = acc[m][n][r];
    }
  }
}

// ---------------- causal flash attention ----------------
// grid: (S/64, B*H), 256 threads. Wave w owns 16 q-rows. Q pre-scaled by 1/sqrt(dk).
// Swapped QK^T: sc = mfma(K_frag, Qt_frag) -> scores^T; lane owns one q-column.
__global__ __launch_bounds__(256) void attn_fwd(const u16* __restrict__ Qd,
                                                const u16* __restrict__ Kd,
                                                const u16* __restrict__ Vtd,
                                                u16* __restrict__ attnb)
{
  __shared__ __align__(16) u16 P_lds[4][16*64];
  const int lane = threadIdx.x & 63, w = threadIdx.x >> 6;
  const int qb = blockIdx.x, bh = blockIdx.y;
  const u16* Qp = Qd  + (size_t)bh * 2048 * 64;
  const u16* Kp = Kd  + (size_t)bh * 2048 * 64;
  const u16* Vp = Vtd + (size_t)bh * 64 * 2048;
  const int fr = lane & 15, k8 = (lane >> 4) * 8, r4 = (lane >> 4) * 4;
  const int q0 = qb * 64 + w * 16;
  const int q_g = q0 + fr;

  s16x8 qf[2];
  qf[0] = *(const s16x8*)(Qp + (size_t)(q0 + fr) * 64 + k8);
  qf[1] = *(const s16x8*)(Qp + (size_t)(q0 + fr) * 64 + 32 + k8);

  f32x4 O[4];
  #pragma unroll
  for (int n = 0; n < 4; n++){ f32x4 z = {0.f,0.f,0.f,0.f}; O[n] = z; }
  float m_run = -1e30f, l_run = 0.f;

  for (int kt = 0; kt <= qb; ++kt){
    const int kb = kt * 64;
    // scores^T (64 keys x 16 q), frag mi holds keys [mi*16, mi*16+16)
    f32x4 sc[4];
    #pragma unroll
    for (int mi = 0; mi < 4; mi++){ f32x4 z = {0.f,0.f,0.f,0.f}; sc[mi] = z; }
    #pragma unroll
    for (int kk = 0; kk < 2; kk++){
      #pragma unroll
      for (int mi = 0; mi < 4; mi++){
        s16x8 kf = *(const s16x8*)(Kp + (size_t)(kb + mi*16 + fr) * 64 + kk*32 + k8);
        sc[mi] = mfma16(kf, qf[kk], sc[mi]);
      }
    }
    // causal mask + per-lane partial max (16 keys for q = q_g)
    float tmax = -1e30f;
    #pragma unroll
    for (int mi = 0; mi < 4; mi++)
      #pragma unroll
      for (int r = 0; r < 4; r++){
        const int s_g = kb + mi*16 + r4 + r;
        float v = sc[mi][r];
        if (s_g > q_g) v = -1e30f;
        sc[mi][r] = v;
        tmax = fmaxf(tmax, v);
      }
    tmax = fmaxf(tmax, __shfl_xor(tmax, 16));
    tmax = fmaxf(tmax, __shfl_xor(tmax, 32));
    const float m_new = fmaxf(m_run, tmax);
    const float corr  = __expf(m_run - m_new);
    float tsum = 0.f;
    u16 pb[4][4];
    #pragma unroll
    for (int mi = 0; mi < 4; mi++)
      #pragma unroll
      for (int r = 0; r < 4; r++){
        const float e = __expf(sc[mi][r] - m_new);
        tsum += e;
        pb[mi][r] = f2bf(e);
      }
    tsum += __shfl_xor(tsum, 16);
    tsum += __shfl_xor(tsum, 32);
    l_run = l_run * corr + tsum;
    m_run = m_new;
    // rescale O (rows q = r4+r; corr lives at lane (q&15))
    float cb[4];
    #pragma unroll
    for (int r = 0; r < 4; r++) cb[r] = __shfl(corr, r4 + r);
    #pragma unroll
    for (int n = 0; n < 4; n++)
      #pragma unroll
      for (int r = 0; r < 4; r++) O[n][r] *= cb[r];
    // P^T (lane-local, D-layout) -> P_lds[q][s]
    #pragma unroll
    for (int mi = 0; mi < 4; mi++){
      u16x4 v = { pb[mi][0], pb[mi][1], pb[mi][2], pb[mi][3] };
      *(u16x4*)(&P_lds[w][fr*64 + mi*16 + r4]) = v;
    }
    // PV: O += P * V   (A-frag from P_lds, B-frag from transposed V, contiguous)
    #pragma unroll
    for (int kk = 0; kk < 2; kk++){
      s16x8 pf = *(const s16x8*)(&P_lds[w][fr*64 + kk*32 + k8]);
      #pragma unroll
      for (int n = 0; n < 4; n++){
        s16x8 vf = *(const s16x8*)(Vp + (size_t)(n*16 + fr) * 2048 + kb + kk*32 + k8);
        O[n] = mfma16(pf, vf, O[n]);
      }
    }
  }
  // finalize: divide by l, store bf16 to (b, s, h, dk)
  const float inv = 1.0f / l_run;
  float ib[4];
  #pragma unroll
  for (int r = 0; r < 4; r++) ib[r] = __shfl(inv, r4 + r);
  const int b = bh >> 4, h = bh & 15;
  #pragma unroll
  for (int n = 0; n < 4; n++){
    const int dk = n*16 + fr;
    #pragma unroll
    for (int r = 0; r < 4; r++){
      const int s = qb*64 + w*16 + r4 + r;
      attnb[(((size_t)b * 2048 + s) * 16 + h) * 64 + dk] = f2bf(O[n][r] * ib[r]);
    }
  }
}

// ---------------- host launch ----------------
extern "C" void kernel_launch(void* const* d_in, const int* in_sizes, int n_in,
                              void* d_out, int out_size, void* d_ws, size_t ws_size,
                              hipStream_t stream)
{
  const float* x    = (const float*)d_in[0];   // (4,2048,1024)
  const float* wqkv = (const float*)d_in[1];   // (3,16,64,1024)
  const float* wo   = (const float*)d_in[2];   // (1024,1024)
  float* out = (float*)d_out;

  char* ws = (char*)d_ws;
  u16* xb    = (u16*)(ws);                       // 16 MiB  (8.4M bf16)
  u16* wqb   = (u16*)(ws + 16777216);            // 6 MiB
  u16* wob   = (u16*)(ws + 23068672);            // 2 MiB
  u16* Qd    = (u16*)(ws + 25165824);            // 16 MiB
  u16* Kd    = (u16*)(ws + 41943040);            // 16 MiB
  u16* Vtd   = (u16*)(ws + 58720256);            // 16 MiB (ends at 72 MiB)
  u16* attnb = xb;                               // reuse: x dead after gemm_qkv

  cvt_f2b<<<2048, 256, 0, stream>>>(x,    xb,  8388608/4);
  cvt_f2b<<<1024, 256, 0, stream>>>(wqkv, wqb, 3145728/4);
  cvt_f2b<<< 512, 256, 0, stream>>>(wo,   wob, 1048576/4);

  gemm_qkv<<<dim3(64, 24), 256, 0, stream>>>(xb, wqb, Qd, Kd, Vtd);
  attn_fwd<<<dim3(32, 64), 256, 0, stream>>>(Qd, Kd, Vtd, attnb);
  gemm_outp<<<dim3(64, 8), 256, 0, stream>>>(attnb, wob, out);
}

// Round 2
// 275.901 us; speedup vs baseline: 2.0675x; 2.0675x over previous
//
#include <hip/hip_runtime.h>
#include <stdint.h>
#include <stddef.h>

typedef unsigned short u16;
typedef float  f32x4  __attribute__((ext_vector_type(4)));
typedef short  s16x8  __attribute__((ext_vector_type(8)));
typedef __bf16 bf16x8 __attribute__((ext_vector_type(8)));
typedef u16    u16x4  __attribute__((ext_vector_type(4)));

#define DEV static __device__ __forceinline__

DEV u16 f2bf(float f){
  uint32_t u = __builtin_bit_cast(uint32_t, f);
  u += 0x7FFFu + ((u >> 16) & 1u);   // round-to-nearest-even
  return (u16)(u >> 16);
}

DEV f32x4 mfma16(s16x8 a, s16x8 b, f32x4 c){
  return __builtin_amdgcn_mfma_f32_16x16x32_bf16(
      __builtin_bit_cast(bf16x8, a), __builtin_bit_cast(bf16x8, b), c, 0, 0, 0);
}

DEV void gl_lds16(const u16* g, u16* l){
  __builtin_amdgcn_global_load_lds(
      (__attribute__((address_space(1))) void*)(g),
      (__attribute__((address_space(3))) void*)(l), 16, 0, 0);
}

// ---------------- fp32 -> bf16 convert ----------------
__global__ __launch_bounds__(256) void cvt_f2b(const float* __restrict__ in,
                                               u16* __restrict__ out, int n4){
  int stride = gridDim.x * blockDim.x;
  for (int i = blockIdx.x * blockDim.x + threadIdx.x; i < n4; i += stride){
    float4 v = *(const float4*)(in + (size_t)i * 4);
    u16x4 o = { f2bf(v.x), f2bf(v.y), f2bf(v.z), f2bf(v.w) };
    *(u16x4*)(out + (size_t)i * 4) = o;
  }
}

// ---------------- 128x128 bf16 GEMM core: C = A * Bw^T ----------------
DEV void gemm_core(const u16* __restrict__ A, const u16* __restrict__ Bw,
                   int K, int bm, int bn, u16* ldsA, u16* ldsB, f32x4 acc[4][4])
{
  const int lane = threadIdx.x & 63;
  const int wave = threadIdx.x >> 6;
  const int wm = (wave >> 1) * 64, wn = (wave & 1) * 64;
  const int l8 = (lane & 7) * 8;
  const int lr = lane >> 3;
  const int fr = lane & 15;
  const int k8 = (lane >> 4) * 8;

  #pragma unroll
  for (int m = 0; m < 4; m++)
    #pragma unroll
    for (int n = 0; n < 4; n++){ f32x4 z = {0.f,0.f,0.f,0.f}; acc[m][n] = z; }

  const int nkt = K >> 6;
  for (int kt = 0; kt < nkt; ++kt){
    const int kb = kt * 64;
    #pragma unroll
    for (int i = 0; i < 4; i++){
      const int c   = wave * 4 + i;
      const int row = c * 8 + lr;
      gl_lds16(A  + (size_t)(bm + row) * K + kb + l8, ldsA + c * 512);
      gl_lds16(Bw + (size_t)(bn + row) * K + kb + l8, ldsB + c * 512);
    }
    __syncthreads();
    #pragma unroll
    for (int kk = 0; kk < 2; ++kk){
      s16x8 af[4], bfr[4];
      #pragma unroll
      for (int m = 0; m < 4; m++) af[m]  = *(const s16x8*)(ldsA + (wm + m*16 + fr)*64 + kk*32 + k8);
      #pragma unroll
      for (int n = 0; n < 4; n++) bfr[n] = *(const s16x8*)(ldsB + (wn + n*16 + fr)*64 + kk*32 + k8);
      #pragma unroll
      for (int m = 0; m < 4; m++)
        #pragma unroll
        for (int n = 0; n < 4; n++)
          acc[m][n] = mfma16(af[m], bfr[n], acc[m][n]);
    }
    __syncthreads();
  }
}

// ---------------- QKV projection ----------------
__global__ __launch_bounds__(256) void gemm_qkv(const u16* __restrict__ xb,
                                                const u16* __restrict__ wb,
                                                u16* __restrict__ Qd,
                                                u16* __restrict__ Kd,
                                                u16* __restrict__ Vtd)
{
  __shared__ __align__(16) u16 ldsA[128*64];
  __shared__ __align__(16) u16 ldsB[128*64];
  f32x4 acc[4][4];
  const int bm = blockIdx.x * 128, bn = blockIdx.y * 128;
  gemm_core(xb, wb, 1024, bm, bn, ldsA, ldsB, acc);

  const int lane = threadIdx.x & 63, wave = threadIdx.x >> 6;
  const int wm = (wave >> 1) * 64, wn = (wave & 1) * 64;
  const int fr = lane & 15, r4 = (lane >> 4) * 4;
  const int q = bn >> 10;

  #pragma unroll
  for (int m = 0; m < 4; m++){
    const int i0 = bm + wm + m*16 + r4;
    const int b  = i0 >> 11;
    const int s0 = i0 & 2047;
    #pragma unroll
    for (int n = 0; n < 4; n++){
      const int ng = bn + wn + n*16 + fr;
      const int h  = (ng >> 6) & 15, kd = ng & 63;
      const size_t bh = (size_t)(b * 16 + h);
      if (q == 0){
        #pragma unroll
        for (int r = 0; r < 4; r++)
          Qd[(bh*2048 + s0 + r)*64 + kd] = f2bf(acc[m][n][r] * 0.125f);
      } else if (q == 1){
        #pragma unroll
        for (int r = 0; r < 4; r++)
          Kd[(bh*2048 + s0 + r)*64 + kd] = f2bf(acc[m][n][r]);
      } else {
        u16x4 v = { f2bf(acc[m][n][0]), f2bf(acc[m][n][1]),
                    f2bf(acc[m][n][2]), f2bf(acc[m][n][3]) };
        *(u16x4*)(Vtd + (bh*64 + kd)*2048 + s0) = v;
      }
    }
  }
}

// ---------------- out projection ----------------
__global__ __launch_bounds__(256) void gemm_outp(const u16* __restrict__ attnb,
                                                 const u16* __restrict__ wob,
                                                 float* __restrict__ C)
{
  __shared__ __align__(16) u16 ldsA[128*64];
  __shared__ __align__(16) u16 ldsB[128*64];
  f32x4 acc[4][4];
  const int bm = blockIdx.x * 128, bn = blockIdx.y * 128;
  gemm_core(attnb, wob, 1024, bm, bn, ldsA, ldsB, acc);

  const int lane = threadIdx.x & 63, wave = threadIdx.x >> 6;
  const int wm = (wave >> 1) * 64, wn = (wave & 1) * 64;
  const int fr = lane & 15, r4 = (lane >> 4) * 4;
  #pragma unroll
  for (int m = 0; m < 4; m++){
    const int i0 = bm + wm + m*16 + r4;
    #pragma unroll
    for (int n = 0; n < 4; n++){
      const int ng = bn + wn + n*16 + fr;
      #pragma unroll
      for (int r = 0; r < 4; r++)
        C[(size_t)(i0 + r) * 1024 + ng] = acc[m][n][r];
    }
  }
}

// ---------------- causal flash attention (v2) ----------------
// grid (16, 64), 256 thr. Block = 128 q-rows, wave = 32 q (2 row-groups of 16).
// K/V tiles (64 keys) staged in LDS double-buffered, XOR-swizzled (chunk ^= row&7).
// QK^T swapped  -> sc cols = q (lane&15).
// PV  swapped   -> O^T cols = q : rescale is per-lane scalar, no bpermute.
__global__ __launch_bounds__(256) void attn_fwd(const u16* __restrict__ Qd,
                                                const u16* __restrict__ Kd,
                                                const u16* __restrict__ Vtd,
                                                u16* __restrict__ attnb)
{
  __shared__ __align__(16) u16 Kl[2][64*64];
  __shared__ __align__(16) u16 Vl[2][64*64];
  __shared__ __align__(16) u16 Pl[4][32*64];

  const int t = threadIdx.x;
  const int lane = t & 63, w = t >> 6;
  const int qb = (int)gridDim.x - 1 - (int)blockIdx.x;   // longest blocks first
  const int bh = blockIdx.y;
  const u16* Qp = Qd  + (size_t)bh * 2048 * 64;
  const u16* Kp = Kd  + (size_t)bh * 2048 * 64;
  const u16* Vp = Vtd + (size_t)bh * 64 * 2048;

  const int fr = lane & 15, g = lane >> 4;
  const int f  = fr & 7;
  const int k8 = g * 8, r4 = g * 4;
  const int q0w   = qb * 128 + w * 32;
  const int wq_hi = q0w + 31;
  const int nkt   = 2 * qb + 2;

  // Q fragments (once, global). b-frag: col=q=fr, k = kk*32+k8..+7
  s16x8 qf[2][2];
  #pragma unroll
  for (int rg = 0; rg < 2; rg++)
    #pragma unroll
    for (int kk = 0; kk < 2; kk++)
      qf[rg][kk] = *(const s16x8*)(Qp + (size_t)(q0w + rg*16 + fr) * 64 + kk*32 + k8);

  f32x4 O[2][4];
  #pragma unroll
  for (int rg = 0; rg < 2; rg++)
    #pragma unroll
    for (int n = 0; n < 4; n++){ f32x4 z = {0.f,0.f,0.f,0.f}; O[rg][n] = z; }
  float m_run[2] = {-1e30f, -1e30f};
  float l_run[2] = {0.f, 0.f};

  // stage tile 0 (swizzled source, linear LDS dest)
  #pragma unroll
  for (int i = 0; i < 2; i++){
    const int L = i*256 + t;
    const int row = L >> 3, c = L & 7;
    const int cs = c ^ (row & 7);
    gl_lds16(Kp + (size_t)row * 64 + cs*8,  Kl[0] + L*8);
    gl_lds16(Vp + (size_t)row * 2048 + cs*8, Vl[0] + L*8);
  }

  for (int kt = 0; kt < nkt; ++kt){
    __syncthreads();              // staged tile kt visible; all reads of other buf done
    const int cur = kt & 1;
    if (kt + 1 < nkt){
      const int kb2 = (kt + 1) * 64;
      u16* Kn = Kl[cur ^ 1]; u16* Vn = Vl[cur ^ 1];
      #pragma unroll
      for (int i = 0; i < 2; i++){
        const int L = i*256 + t;
        const int row = L >> 3, c = L & 7;
        const int cs = c ^ (row & 7);
        gl_lds16(Kp + (size_t)(kb2 + row) * 64 + cs*8, Kn + L*8);
        gl_lds16(Vp + (size_t)row * 2048 + kb2 + cs*8, Vn + L*8);
      }
    }
    const int kb = kt * 64;
    if (kb > wq_hi) continue;     // fully-masked tile for this wave (barrier count uniform)

    const u16* Kc = Kl[cur];
    const u16* Vc = Vl[cur];

    // ---- QK^T: sc[rg][mi], cols = q, rows = keys mi*16+r4+r ----
    f32x4 sc[2][4];
    #pragma unroll
    for (int rg = 0; rg < 2; rg++)
      #pragma unroll
      for (int mi = 0; mi < 4; mi++){ f32x4 z = {0.f,0.f,0.f,0.f}; sc[rg][mi] = z; }
    #pragma unroll
    for (int kk = 0; kk < 2; kk++)
      #pragma unroll
      for (int mi = 0; mi < 4; mi++){
        s16x8 kf = *(const s16x8*)(Kc + (mi*16 + fr)*64 + ((kk*4 + g) ^ f)*8);
        sc[0][mi] = mfma16(kf, qf[0][kk], sc[0][mi]);
        sc[1][mi] = mfma16(kf, qf[1][kk], sc[1][mi]);
      }

    // ---- online softmax per row-group (independent chains) ----
    #pragma unroll
    for (int rg = 0; rg < 2; rg++){
      const int q_g = q0w + rg*16 + fr;
      float tmax = -1e30f;
      if (kb + 63 > q0w + rg*16){   // wave-uniform: masking needed
        #pragma unroll
        for (int mi = 0; mi < 4; mi++)
          #pragma unroll
          for (int r = 0; r < 4; r++){
            const int s_g = kb + mi*16 + r4 + r;
            float v = sc[rg][mi][r];
            v = (s_g > q_g) ? -1e30f : v;
            sc[rg][mi][r] = v;
            tmax = fmaxf(tmax, v);
          }
      } else {
        #pragma unroll
        for (int mi = 0; mi < 4; mi++)
          #pragma unroll
          for (int r = 0; r < 4; r++)
            tmax = fmaxf(tmax, sc[rg][mi][r]);
      }
      tmax = fmaxf(tmax, __shfl_xor(tmax, 16));
      tmax = fmaxf(tmax, __shfl_xor(tmax, 32));
      const float m_new = fmaxf(m_run[rg], tmax);
      const float corr  = __expf(m_run[rg] - m_new);
      m_run[rg] = m_new;
      float tsum = 0.f;
      u16 pb[4][4];
      #pragma unroll
      for (int mi = 0; mi < 4; mi++)
        #pragma unroll
        for (int r = 0; r < 4; r++){
          const float e = __expf(sc[rg][mi][r] - m_new);
          tsum += e;
          pb[mi][r] = f2bf(e);
        }
      tsum += __shfl_xor(tsum, 16);
      tsum += __shfl_xor(tsum, 32);
      l_run[rg] = l_run[rg] * corr + tsum;
      #pragma unroll
      for (int n = 0; n < 4; n++)
        #pragma unroll
        for (int r = 0; r < 4; r++)
          O[rg][n][r] *= corr;               // per-lane scalar (O^T cols = q)
      // P -> LDS (swizzled): row = rg*16+fr (q), keys mi*16+4g..+3, 8B store
      const int prow = rg*16 + fr;
      #pragma unroll
      for (int mi = 0; mi < 4; mi++){
        u16x4 v = { pb[mi][0], pb[mi][1], pb[mi][2], pb[mi][3] };
        *(u16x4*)(&Pl[w][prow*64 + ((((mi*2 + (g>>1)) ^ f) << 3) + (g & 1)*4)]) = v;
      }
    }

    // ---- PV (swapped): O^T[n] += mfma(V^T frag, P frag) ----
    #pragma unroll
    for (int kk = 0; kk < 2; kk++){
      s16x8 pf0 = *(const s16x8*)(&Pl[w][(fr)*64      + ((kk*4 + g) ^ f)*8]);
      s16x8 pf1 = *(const s16x8*)(&Pl[w][(16 + fr)*64 + ((kk*4 + g) ^ f)*8]);
      #pragma unroll
      for (int n = 0; n < 4; n++){
        s16x8 vf = *(const s16x8*)(Vc + (n*16 + fr)*64 + ((kk*4 + g) ^ f)*8);
        O[0][n] = mfma16(vf, pf0, O[0][n]);
        O[1][n] = mfma16(vf, pf1, O[1][n]);
      }
    }
  }

  // ---- epilogue: O^T rows = dk (n*16+r4+r), col = q (fr) ----
  const int b = bh >> 4, h = bh & 15;
  #pragma unroll
  for (int rg = 0; rg < 2; rg++){
    const float inv = 1.0f / l_run[rg];
    const int s = q0w + rg*16 + fr;
    #pragma unroll
    for (int n = 0; n < 4; n++){
      u16x4 v = { f2bf(O[rg][n][0]*inv), f2bf(O[rg][n][1]*inv),
                  f2bf(O[rg][n][2]*inv), f2bf(O[rg][n][3]*inv) };
      *(u16x4*)(attnb + (((size_t)b*2048 + s)*16 + h)*64 + n*16 + r4) = v;
    }
  }
}

// ---------------- host launch ----------------
extern "C" void kernel_launch(void* const* d_in, const int* in_sizes, int n_in,
                              void* d_out, int out_size, void* d_ws, size_t ws_size,
                              hipStream_t stream)
{
  const float* x    = (const float*)d_in[0];   // (4,2048,1024)
  const float* wqkv = (const float*)d_in[1];   // (3,16,64,1024)
  const float* wo   = (const float*)d_in[2];   // (1024,1024)
  float* out = (float*)d_out;

  char* ws = (char*)d_ws;
  u16* xb    = (u16*)(ws);
  u16* wqb   = (u16*)(ws + 16777216);
  u16* wob   = (u16*)(ws + 23068672);
  u16* Qd    = (u16*)(ws + 25165824);
  u16* Kd    = (u16*)(ws + 41943040);
  u16* Vtd   = (u16*)(ws + 58720256);
  u16* attnb = xb;                               // x dead after gemm_qkv

  cvt_f2b<<<2048, 256, 0, stream>>>(x,    xb,  8388608/4);
  cvt_f2b<<<1024, 256, 0, stream>>>(wqkv, wqb, 3145728/4);
  cvt_f2b<<< 512, 256, 0, stream>>>(wo,   wob, 1048576/4);

  gemm_qkv<<<dim3(64, 24), 256, 0, stream>>>(xb, wqb, Qd, Kd, Vtd);
  attn_fwd<<<dim3(16, 64), 256, 0, stream>>>(Qd, Kd, Vtd, attnb);
  gemm_outp<<<dim3(64, 8), 256, 0, stream>>>(attnb, wob, out);
}

// Round 4
// 272.894 us; speedup vs baseline: 2.0903x; 1.0110x over previous
//
#include <hip/hip_runtime.h>
#include <stdint.h>
#include <stddef.h>

typedef unsigned short u16;
typedef float  f32x4  __attribute__((ext_vector_type(4)));
typedef short  s16x8  __attribute__((ext_vector_type(8)));
typedef short  s16x4  __attribute__((ext_vector_type(4)));
typedef __bf16 bf16x8 __attribute__((ext_vector_type(8)));
typedef __bf16 bf16x4 __attribute__((ext_vector_type(4)));
typedef u16    u16x4  __attribute__((ext_vector_type(4)));

#define DEV static __device__ __forceinline__

DEV u16 f2bf(float f){
  uint32_t u = __builtin_bit_cast(uint32_t, f);
  u += 0x7FFFu + ((u >> 16) & 1u);   // round-to-nearest-even
  return (u16)(u >> 16);
}

DEV f32x4 mfma16(s16x8 a, s16x8 b, f32x4 c){
  return __builtin_amdgcn_mfma_f32_16x16x32_bf16(
      __builtin_bit_cast(bf16x8, a), __builtin_bit_cast(bf16x8, b), c, 0, 0, 0);
}

// K=16 bf16 MFMA (gfx90a-era builtin, carried to gfx950):
// B-frag layout == QK^T D-layout -> PV needs no P re-layout.
DEV f32x4 mfma16k(s16x4 a, s16x4 b, f32x4 c){
  return __builtin_amdgcn_mfma_f32_16x16x16bf16_1k(a, b, c, 0, 0, 0);
}

DEV float exp2_fast(float x){
  return __builtin_exp2f(x);   // maps to v_exp_f32 on device with fast-math-free correctness
}

DEV void gl_lds16(const u16* g, u16* l){
  __builtin_amdgcn_global_load_lds(
      (__attribute__((address_space(1))) void*)(g),
      (__attribute__((address_space(3))) void*)(l), 16, 0, 0);
}

// ---------------- fp32 -> bf16 convert ----------------
__global__ __launch_bounds__(256) void cvt_f2b(const float* __restrict__ in,
                                               u16* __restrict__ out, int n4){
  int stride = gridDim.x * blockDim.x;
  for (int i = blockIdx.x * blockDim.x + threadIdx.x; i < n4; i += stride){
    float4 v = *(const float4*)(in + (size_t)i * 4);
    u16x4 o = { f2bf(v.x), f2bf(v.y), f2bf(v.z), f2bf(v.w) };
    *(u16x4*)(out + (size_t)i * 4) = o;
  }
}

// ---------------- 128x128 bf16 GEMM core: C = A * Bw^T ----------------
DEV void gemm_core(const u16* __restrict__ A, const u16* __restrict__ Bw,
                   int K, int bm, int bn, u16* ldsA, u16* ldsB, f32x4 acc[4][4])
{
  const int lane = threadIdx.x & 63;
  const int wave = threadIdx.x >> 6;
  const int wm = (wave >> 1) * 64, wn = (wave & 1) * 64;
  const int l8 = (lane & 7) * 8;
  const int lr = lane >> 3;
  const int fr = lane & 15;
  const int k8 = (lane >> 4) * 8;

  #pragma unroll
  for (int m = 0; m < 4; m++)
    #pragma unroll
    for (int n = 0; n < 4; n++){ f32x4 z = {0.f,0.f,0.f,0.f}; acc[m][n] = z; }

  const int nkt = K >> 6;
  for (int kt = 0; kt < nkt; ++kt){
    const int kb = kt * 64;
    #pragma unroll
    for (int i = 0; i < 4; i++){
      const int c   = wave * 4 + i;
      const int row = c * 8 + lr;
      gl_lds16(A  + (size_t)(bm + row) * K + kb + l8, ldsA + c * 512);
      gl_lds16(Bw + (size_t)(bn + row) * K + kb + l8, ldsB + c * 512);
    }
    __syncthreads();
    #pragma unroll
    for (int kk = 0; kk < 2; ++kk){
      s16x8 af[4], bfr[4];
      #pragma unroll
      for (int m = 0; m < 4; m++) af[m]  = *(const s16x8*)(ldsA + (wm + m*16 + fr)*64 + kk*32 + k8);
      #pragma unroll
      for (int n = 0; n < 4; n++) bfr[n] = *(const s16x8*)(ldsB + (wn + n*16 + fr)*64 + kk*32 + k8);
      #pragma unroll
      for (int m = 0; m < 4; m++)
        #pragma unroll
        for (int n = 0; n < 4; n++)
          acc[m][n] = mfma16(af[m], bfr[n], acc[m][n]);
    }
    __syncthreads();
  }
}

// ---------------- QKV projection ----------------
// Q pre-scaled by log2(e)/sqrt(dk) so attention works in exp2 domain.
__global__ __launch_bounds__(256) void gemm_qkv(const u16* __restrict__ xb,
                                                const u16* __restrict__ wb,
                                                u16* __restrict__ Qd,
                                                u16* __restrict__ Kd,
                                                u16* __restrict__ Vtd)
{
  __shared__ __align__(16) u16 ldsA[128*64];
  __shared__ __align__(16) u16 ldsB[128*64];
  f32x4 acc[4][4];
  const int bm = blockIdx.x * 128, bn = blockIdx.y * 128;
  gemm_core(xb, wb, 1024, bm, bn, ldsA, ldsB, acc);

  const int lane = threadIdx.x & 63, wave = threadIdx.x >> 6;
  const int wm = (wave >> 1) * 64, wn = (wave & 1) * 64;
  const int fr = lane & 15, r4 = (lane >> 4) * 4;
  const int q = bn >> 10;

  #pragma unroll
  for (int m = 0; m < 4; m++){
    const int i0 = bm + wm + m*16 + r4;
    const int b  = i0 >> 11;
    const int s0 = i0 & 2047;
    #pragma unroll
    for (int n = 0; n < 4; n++){
      const int ng = bn + wn + n*16 + fr;
      const int h  = (ng >> 6) & 15, kd = ng & 63;
      const size_t bh = (size_t)(b * 16 + h);
      if (q == 0){
        #pragma unroll
        for (int r = 0; r < 4; r++)
          Qd[(bh*2048 + s0 + r)*64 + kd] = f2bf(acc[m][n][r] * 0.18033688011112042f);
      } else if (q == 1){
        #pragma unroll
        for (int r = 0; r < 4; r++)
          Kd[(bh*2048 + s0 + r)*64 + kd] = f2bf(acc[m][n][r]);
      } else {
        u16x4 v = { f2bf(acc[m][n][0]), f2bf(acc[m][n][1]),
                    f2bf(acc[m][n][2]), f2bf(acc[m][n][3]) };
        *(u16x4*)(Vtd + (bh*64 + kd)*2048 + s0) = v;
      }
    }
  }
}

// ---------------- out projection ----------------
__global__ __launch_bounds__(256) void gemm_outp(const u16* __restrict__ attnb,
                                                 const u16* __restrict__ wob,
                                                 float* __restrict__ C)
{
  __shared__ __align__(16) u16 ldsA[128*64];
  __shared__ __align__(16) u16 ldsB[128*64];
  f32x4 acc[4][4];
  const int bm = blockIdx.x * 128, bn = blockIdx.y * 128;
  gemm_core(attnb, wob, 1024, bm, bn, ldsA, ldsB, acc);

  const int lane = threadIdx.x & 63, wave = threadIdx.x >> 6;
  const int wm = (wave >> 1) * 64, wn = (wave & 1) * 64;
  const int fr = lane & 15, r4 = (lane >> 4) * 4;
  #pragma unroll
  for (int m = 0; m < 4; m++){
    const int i0 = bm + wm + m*16 + r4;
    #pragma unroll
    for (int n = 0; n < 4; n++){
      const int ng = bn + wn + n*16 + fr;
      #pragma unroll
      for (int r = 0; r < 4; r++)
        C[(size_t)(i0 + r) * 1024 + ng] = acc[m][n][r];
    }
  }
}

// ---------------- causal flash attention (v3) ----------------
// Flat grid 1024, 256 thr. XCD-aware decode: all 16 q-blocks of one (b,h)
// land on the same XCD (wgid%8) -> K/V L2-resident per XCD.
// Block = 128 q rows; wave = 32 q (2 row-groups). K/V LDS dbuf (32 KiB only),
// 4 blocks/CU co-resident. QK^T swapped (sc cols=q). PV via 16x16x16 MFMA
// directly on the QK^T output fragments (no P LDS, no redistribution).
// exp2-domain softmax (Q pre-scaled by log2e), defer-max threshold 8.
__global__ __launch_bounds__(256, 4) void attn_fwd(const u16* __restrict__ Qd,
                                                   const u16* __restrict__ Kd,
                                                   const u16* __restrict__ Vtd,
                                                   u16* __restrict__ attnb)
{
  __shared__ __align__(16) u16 Kl[2][64*64];
  __shared__ __align__(16) u16 Vl[2][64*64];

  const int t = threadIdx.x;
  const int lane = t & 63, w = t >> 6;
  const int wg = blockIdx.x;
  const int bh = (wg & 7) + 8 * (wg >> 7);         // same bh -> same XCD
  const int qb = 15 - ((wg >> 3) & 15);            // longest-first within stream
  const u16* Qp = Qd  + (size_t)bh * 2048 * 64;
  const u16* Kp = Kd  + (size_t)bh * 2048 * 64;
  const u16* Vp = Vtd + (size_t)bh * 64 * 2048;

  const int fr = lane & 15, g = lane >> 4;
  const int f  = fr & 7;
  const int k8 = g * 8, r4 = g * 4;
  const int q0w   = qb * 128 + w * 32;
  const int wq_hi = q0w + 31;
  const int nkt   = 2 * qb + 2;

  // Q fragments (global, once). col=q=fr, k = kk*32+k8..+7
  s16x8 qf[2][2];
  #pragma unroll
  for (int rg = 0; rg < 2; rg++)
    #pragma unroll
    for (int kk = 0; kk < 2; kk++)
      qf[rg][kk] = *(const s16x8*)(Qp + (size_t)(q0w + rg*16 + fr) * 64 + kk*32 + k8);

  f32x4 O[2][4];
  #pragma unroll
  for (int rg = 0; rg < 2; rg++)
    #pragma unroll
    for (int n = 0; n < 4; n++){ f32x4 z = {0.f,0.f,0.f,0.f}; O[rg][n] = z; }
  float m_run[2] = {-1e30f, -1e30f};
  float l_run[2] = {0.f, 0.f};

  // stage tile 0 (swizzled source, linear LDS dest)
  #pragma unroll
  for (int i = 0; i < 2; i++){
    const int L = i*256 + t;
    const int row = L >> 3, c = L & 7;
    const int cs = c ^ (row & 7);
    gl_lds16(Kp + (size_t)row * 64 + cs*8,   Kl[0] + L*8);
    gl_lds16(Vp + (size_t)row * 2048 + cs*8, Vl[0] + L*8);
  }

  for (int kt = 0; kt < nkt; ++kt){
    __syncthreads();
    const int cur = kt & 1;
    if (kt + 1 < nkt){
      const int kb2 = (kt + 1) * 64;
      u16* Kn = Kl[cur ^ 1]; u16* Vn = Vl[cur ^ 1];
      #pragma unroll
      for (int i = 0; i < 2; i++){
        const int L = i*256 + t;
        const int row = L >> 3, c = L & 7;
        const int cs = c ^ (row & 7);
        gl_lds16(Kp + (size_t)(kb2 + row) * 64 + cs*8, Kn + L*8);
        gl_lds16(Vp + (size_t)row * 2048 + kb2 + cs*8, Vn + L*8);
      }
    }
    const int kb = kt * 64;
    if (kb > wq_hi) continue;     // fully-masked tile for this wave

    const u16* Kc = Kl[cur];
    const u16* Vc = Vl[cur];

    // ---- QK^T: sc[rg][mi] cols=q(fr), keys mi*16+4g+r ----
    f32x4 sc[2][4];
    #pragma unroll
    for (int rg = 0; rg < 2; rg++)
      #pragma unroll
      for (int mi = 0; mi < 4; mi++){ f32x4 z = {0.f,0.f,0.f,0.f}; sc[rg][mi] = z; }
    #pragma unroll
    for (int kk = 0; kk < 2; kk++)
      #pragma unroll
      for (int mi = 0; mi < 4; mi++){
        s16x8 kf = *(const s16x8*)(Kc + (mi*16 + fr)*64 + ((kk*4 + g) ^ f)*8);
        sc[0][mi] = mfma16(kf, qf[0][kk], sc[0][mi]);
        sc[1][mi] = mfma16(kf, qf[1][kk], sc[1][mi]);
      }

    // ---- online softmax (exp2 domain), P stays in registers ----
    s16x4 pb[2][4];
    #pragma unroll
    for (int rg = 0; rg < 2; rg++){
      const int q_g = q0w + rg*16 + fr;
      float tmax = -1e30f;
      if (kb + 63 > q0w + rg*16){
        #pragma unroll
        for (int mi = 0; mi < 4; mi++)
          #pragma unroll
          for (int r = 0; r < 4; r++){
            const int s_g = kb + mi*16 + r4 + r;
            float v = sc[rg][mi][r];
            v = (s_g > q_g) ? -1e30f : v;
            sc[rg][mi][r] = v;
            tmax = fmaxf(tmax, v);
          }
      } else {
        #pragma unroll
        for (int mi = 0; mi < 4; mi++)
          #pragma unroll
          for (int r = 0; r < 4; r++)
            tmax = fmaxf(tmax, sc[rg][mi][r]);
      }
      tmax = fmaxf(tmax, __shfl_xor(tmax, 16));
      tmax = fmaxf(tmax, __shfl_xor(tmax, 32));
      float m_new = m_run[rg];
      if (!__all(tmax <= m_run[rg] + 8.f)){   // T13 defer-max (wave-uniform)
        m_new = fmaxf(m_run[rg], tmax);
        const float corr = exp2_fast(m_run[rg] - m_new);
        m_run[rg] = m_new;
        l_run[rg] *= corr;
        #pragma unroll
        for (int n = 0; n < 4; n++)
          #pragma unroll
          for (int r = 0; r < 4; r++)
            O[rg][n][r] *= corr;              // per-lane scalar (O^T cols=q)
      }
      float tsum = 0.f;
      #pragma unroll
      for (int mi = 0; mi < 4; mi++){
        f32x4 e;
        #pragma unroll
        for (int r = 0; r < 4; r++){
          e[r] = exp2_fast(sc[rg][mi][r] - m_new);
          tsum += e[r];
        }
        pb[rg][mi] = __builtin_bit_cast(s16x4, __builtin_convertvector(e, bf16x4));
      }
      tsum += __shfl_xor(tsum, 16);
      tsum += __shfl_xor(tsum, 32);
      l_run[rg] += tsum;
    }

    // ---- PV via 16x16x16 MFMA: O^T[n] += V^T-frag * pb[mi] ----
    #pragma unroll
    for (int mi = 0; mi < 4; mi++){
      #pragma unroll
      for (int n = 0; n < 4; n++){
        s16x4 vf = *(const s16x4*)(Vc + (n*16 + fr)*64 + ((2*mi + (g >> 1)) ^ f)*8 + (g & 1)*4);
        O[0][n] = mfma16k(vf, pb[0][mi], O[0][n]);
        O[1][n] = mfma16k(vf, pb[1][mi], O[1][n]);
      }
    }
  }

  // ---- epilogue: O^T rows = dk (n*16+r4+r), col = q (fr) ----
  const int b = bh >> 4, h = bh & 15;
  #pragma unroll
  for (int rg = 0; rg < 2; rg++){
    const float inv = 1.0f / l_run[rg];
    const int s = q0w + rg*16 + fr;
    #pragma unroll
    for (int n = 0; n < 4; n++){
      u16x4 v = { f2bf(O[rg][n][0]*inv), f2bf(O[rg][n][1]*inv),
                  f2bf(O[rg][n][2]*inv), f2bf(O[rg][n][3]*inv) };
      *(u16x4*)(attnb + (((size_t)b*2048 + s)*16 + h)*64 + n*16 + r4) = v;
    }
  }
}

// ---------------- host launch ----------------
extern "C" void kernel_launch(void* const* d_in, const int* in_sizes, int n_in,
                              void* d_out, int out_size, void* d_ws, size_t ws_size,
                              hipStream_t stream)
{
  const float* x    = (const float*)d_in[0];   // (4,2048,1024)
  const float* wqkv = (const float*)d_in[1];   // (3,16,64,1024)
  const float* wo   = (const float*)d_in[2];   // (1024,1024)
  float* out = (float*)d_out;

  char* ws = (char*)d_ws;
  u16* xb    = (u16*)(ws);
  u16* wqb   = (u16*)(ws + 16777216);
  u16* wob   = (u16*)(ws + 23068672);
  u16* Qd    = (u16*)(ws + 25165824);
  u16* Kd    = (u16*)(ws + 41943040);
  u16* Vtd   = (u16*)(ws + 58720256);
  u16* attnb = xb;                               // x dead after gemm_qkv

  cvt_f2b<<<2048, 256, 0, stream>>>(x,    xb,  8388608/4);
  cvt_f2b<<<1024, 256, 0, stream>>>(wqkv, wqb, 3145728/4);
  cvt_f2b<<< 512, 256, 0, stream>>>(wo,   wob, 1048576/4);

  gemm_qkv<<<dim3(64, 24), 256, 0, stream>>>(xb, wqb, Qd, Kd, Vtd);
  attn_fwd<<<dim3(1024), 256, 0, stream>>>(Qd, Kd, Vtd, attnb);
  gemm_outp<<<dim3(64, 8), 256, 0, stream>>>(attnb, wob, out);
}

// Round 5
// 216.374 us; speedup vs baseline: 2.6363x; 1.2612x over previous
//
#include <hip/hip_runtime.h>
#include <stdint.h>
#include <stddef.h>

typedef unsigned short u16;
typedef float  f32x4  __attribute__((ext_vector_type(4)));
typedef short  s16x8  __attribute__((ext_vector_type(8)));
typedef short  s16x4  __attribute__((ext_vector_type(4)));
typedef __bf16 bf16x8 __attribute__((ext_vector_type(8)));
typedef __bf16 bf16x4 __attribute__((ext_vector_type(4)));
typedef u16    u16x4  __attribute__((ext_vector_type(4)));

#define DEV static __device__ __forceinline__

DEV u16 f2bf(float f){
  uint32_t u = __builtin_bit_cast(uint32_t, f);
  u += 0x7FFFu + ((u >> 16) & 1u);   // round-to-nearest-even
  return (u16)(u >> 16);
}

DEV f32x4 mfma16(s16x8 a, s16x8 b, f32x4 c){
  return __builtin_amdgcn_mfma_f32_16x16x32_bf16(
      __builtin_bit_cast(bf16x8, a), __builtin_bit_cast(bf16x8, b), c, 0, 0, 0);
}

// K=16 bf16 MFMA: B-frag layout == QK^T D-layout -> PV needs no P re-layout.
DEV f32x4 mfma16k(s16x4 a, s16x4 b, f32x4 c){
  return __builtin_amdgcn_mfma_f32_16x16x16bf16_1k(a, b, c, 0, 0, 0);
}

DEV float exp2_fast(float x){ return __builtin_exp2f(x); }

DEV void gl_lds16(const u16* g, u16* l){
  __builtin_amdgcn_global_load_lds(
      (__attribute__((address_space(1))) void*)(g),
      (__attribute__((address_space(3))) void*)(l), 16, 0, 0);
}

// ---------------- fp32 -> bf16 convert ----------------
__global__ __launch_bounds__(256) void cvt_f2b(const float* __restrict__ in,
                                               u16* __restrict__ out, int n4){
  int stride = gridDim.x * blockDim.x;
  for (int i = blockIdx.x * blockDim.x + threadIdx.x; i < n4; i += stride){
    float4 v = *(const float4*)(in + (size_t)i * 4);
    u16x4 o = { f2bf(v.x), f2bf(v.y), f2bf(v.z), f2bf(v.w) };
    *(u16x4*)(out + (size_t)i * 4) = o;
  }
}

// ---------------- 128x128 bf16 GEMM core: C = A * Bw^T ----------------
DEV void gemm_core(const u16* __restrict__ A, const u16* __restrict__ Bw,
                   int K, int bm, int bn, u16* ldsA, u16* ldsB, f32x4 acc[4][4])
{
  const int lane = threadIdx.x & 63;
  const int wave = threadIdx.x >> 6;
  const int wm = (wave >> 1) * 64, wn = (wave & 1) * 64;
  const int l8 = (lane & 7) * 8;
  const int lr = lane >> 3;
  const int fr = lane & 15;
  const int k8 = (lane >> 4) * 8;

  #pragma unroll
  for (int m = 0; m < 4; m++)
    #pragma unroll
    for (int n = 0; n < 4; n++){ f32x4 z = {0.f,0.f,0.f,0.f}; acc[m][n] = z; }

  const int nkt = K >> 6;
  for (int kt = 0; kt < nkt; ++kt){
    const int kb = kt * 64;
    #pragma unroll
    for (int i = 0; i < 4; i++){
      const int c   = wave * 4 + i;
      const int row = c * 8 + lr;
      gl_lds16(A  + (size_t)(bm + row) * K + kb + l8, ldsA + c * 512);
      gl_lds16(Bw + (size_t)(bn + row) * K + kb + l8, ldsB + c * 512);
    }
    __syncthreads();
    #pragma unroll
    for (int kk = 0; kk < 2; ++kk){
      s16x8 af[4], bfr[4];
      #pragma unroll
      for (int m = 0; m < 4; m++) af[m]  = *(const s16x8*)(ldsA + (wm + m*16 + fr)*64 + kk*32 + k8);
      #pragma unroll
      for (int n = 0; n < 4; n++) bfr[n] = *(const s16x8*)(ldsB + (wn + n*16 + fr)*64 + kk*32 + k8);
      #pragma unroll
      for (int m = 0; m < 4; m++)
        #pragma unroll
        for (int n = 0; n < 4; n++)
          acc[m][n] = mfma16(af[m], bfr[n], acc[m][n]);
    }
    __syncthreads();
  }
}

// ---------------- QKV projection ----------------
// Q pre-scaled by log2(e)/sqrt(dk) so attention works in exp2 domain.
__global__ __launch_bounds__(256) void gemm_qkv(const u16* __restrict__ xb,
                                                const u16* __restrict__ wb,
                                                u16* __restrict__ Qd,
                                                u16* __restrict__ Kd,
                                                u16* __restrict__ Vtd)
{
  __shared__ __align__(16) u16 ldsA[128*64];
  __shared__ __align__(16) u16 ldsB[128*64];
  f32x4 acc[4][4];
  const int bm = blockIdx.x * 128, bn = blockIdx.y * 128;
  gemm_core(xb, wb, 1024, bm, bn, ldsA, ldsB, acc);

  const int lane = threadIdx.x & 63, wave = threadIdx.x >> 6;
  const int wm = (wave >> 1) * 64, wn = (wave & 1) * 64;
  const int fr = lane & 15, r4 = (lane >> 4) * 4;
  const int q = bn >> 10;

  #pragma unroll
  for (int m = 0; m < 4; m++){
    const int i0 = bm + wm + m*16 + r4;
    const int b  = i0 >> 11;
    const int s0 = i0 & 2047;
    #pragma unroll
    for (int n = 0; n < 4; n++){
      const int ng = bn + wn + n*16 + fr;
      const int h  = (ng >> 6) & 15, kd = ng & 63;
      const size_t bh = (size_t)(b * 16 + h);
      if (q == 0){
        #pragma unroll
        for (int r = 0; r < 4; r++)
          Qd[(bh*2048 + s0 + r)*64 + kd] = f2bf(acc[m][n][r] * 0.18033688011112042f);
      } else if (q == 1){
        #pragma unroll
        for (int r = 0; r < 4; r++)
          Kd[(bh*2048 + s0 + r)*64 + kd] = f2bf(acc[m][n][r]);
      } else {
        u16x4 v = { f2bf(acc[m][n][0]), f2bf(acc[m][n][1]),
                    f2bf(acc[m][n][2]), f2bf(acc[m][n][3]) };
        *(u16x4*)(Vtd + (bh*64 + kd)*2048 + s0) = v;
      }
    }
  }
}

// ---------------- out projection ----------------
__global__ __launch_bounds__(256) void gemm_outp(const u16* __restrict__ attnb,
                                                 const u16* __restrict__ wob,
                                                 float* __restrict__ C)
{
  __shared__ __align__(16) u16 ldsA[128*64];
  __shared__ __align__(16) u16 ldsB[128*64];
  f32x4 acc[4][4];
  const int bm = blockIdx.x * 128, bn = blockIdx.y * 128;
  gemm_core(attnb, wob, 1024, bm, bn, ldsA, ldsB, acc);

  const int lane = threadIdx.x & 63, wave = threadIdx.x >> 6;
  const int wm = (wave >> 1) * 64, wn = (wave & 1) * 64;
  const int fr = lane & 15, r4 = (lane >> 4) * 4;
  #pragma unroll
  for (int m = 0; m < 4; m++){
    const int i0 = bm + wm + m*16 + r4;
    #pragma unroll
    for (int n = 0; n < 4; n++){
      const int ng = bn + wn + n*16 + fr;
      #pragma unroll
      for (int r = 0; r < 4; r++)
        C[(size_t)(i0 + r) * 1024 + ng] = acc[m][n][r];
    }
  }
}

// ---- one 64-key tile for one 32-q chunk-half (2 row groups) ----
DEV void chunk_step(const u16* Kc, const u16* Vc, int kb, int q0c,
                    const s16x8 (&qfc)[2][2], f32x4 (&Oc)[2][4],
                    float* m2, float* l2,
                    int fr, int g, int f, int r4)
{
  // QK^T: sc[rg][mi] cols=q(fr), keys mi*16+4g+r
  f32x4 sc[2][4];
  #pragma unroll
  for (int rg = 0; rg < 2; rg++)
    #pragma unroll
    for (int mi = 0; mi < 4; mi++){ f32x4 z = {0.f,0.f,0.f,0.f}; sc[rg][mi] = z; }
  __builtin_amdgcn_s_setprio(1);
  #pragma unroll
  for (int kk = 0; kk < 2; kk++)
    #pragma unroll
    for (int mi = 0; mi < 4; mi++){
      s16x8 kf = *(const s16x8*)(Kc + (mi*16 + fr)*64 + ((kk*4 + g) ^ f)*8);
      sc[0][mi] = mfma16(kf, qfc[0][kk], sc[0][mi]);
      sc[1][mi] = mfma16(kf, qfc[1][kk], sc[1][mi]);
    }
  __builtin_amdgcn_s_setprio(0);

  // online softmax (exp2 domain), P stays in registers
  s16x4 pb[2][4];
  #pragma unroll
  for (int rg = 0; rg < 2; rg++){
    const int q_g = q0c + rg*16 + fr;
    float tmax = -1e30f;
    if (kb + 63 > q0c + rg*16){
      #pragma unroll
      for (int mi = 0; mi < 4; mi++)
        #pragma unroll
        for (int r = 0; r < 4; r++){
          const int s_g = kb + mi*16 + r4 + r;
          float v = sc[rg][mi][r];
          v = (s_g > q_g) ? -1e30f : v;
          sc[rg][mi][r] = v;
          tmax = fmaxf(tmax, v);
        }
    } else {
      #pragma unroll
      for (int mi = 0; mi < 4; mi++)
        #pragma unroll
        for (int r = 0; r < 4; r++)
          tmax = fmaxf(tmax, sc[rg][mi][r]);
    }
    tmax = fmaxf(tmax, __shfl_xor(tmax, 16));
    tmax = fmaxf(tmax, __shfl_xor(tmax, 32));
    float m_new = m2[rg];
    if (!__all(tmax <= m2[rg] + 8.f)){   // T13 defer-max (wave-uniform)
      m_new = fmaxf(m2[rg], tmax);
      const float corr = exp2_fast(m2[rg] - m_new);
      m2[rg] = m_new;
      l2[rg] *= corr;
      #pragma unroll
      for (int n = 0; n < 4; n++)
        #pragma unroll
        for (int r = 0; r < 4; r++)
          Oc[rg][n][r] *= corr;          // per-lane scalar (O^T cols=q)
    }
    float tsum = 0.f;
    #pragma unroll
    for (int mi = 0; mi < 4; mi++){
      f32x4 e;
      #pragma unroll
      for (int r = 0; r < 4; r++){
        e[r] = exp2_fast(sc[rg][mi][r] - m_new);
        tsum += e[r];
      }
      pb[rg][mi] = __builtin_bit_cast(s16x4, __builtin_convertvector(e, bf16x4));
    }
    tsum += __shfl_xor(tsum, 16);
    tsum += __shfl_xor(tsum, 32);
    l2[rg] += tsum;
  }

  // PV via 16x16x16 MFMA: O^T[n] += V^T-frag * pb[mi]
  __builtin_amdgcn_s_setprio(1);
  #pragma unroll
  for (int mi = 0; mi < 4; mi++){
    #pragma unroll
    for (int n = 0; n < 4; n++){
      s16x4 vf = *(const s16x4*)(Vc + (n*16 + fr)*64 + ((2*mi + (g >> 1)) ^ f)*8 + (g & 1)*4);
      Oc[0][n] = mfma16k(vf, pb[0][mi], Oc[0][n]);
      Oc[1][n] = mfma16k(vf, pb[1][mi], Oc[1][n]);
    }
  }
  __builtin_amdgcn_s_setprio(0);
}

// ---------------- causal flash attention (v4: paired chunks) ----------------
// Grid 512 flat. Block = chunk-hi (qh in 8..15, 128 q rows) + chunk-lo (ql=15-qh):
// per-wave work is 68 rg-tiles for EVERY block -> zero causal imbalance.
// All 512 blocks co-resident (2/CU, LDS 32 KiB, 8 waves/CU constant).
// XCD decode: 8 bh per XCD -> K/V (4 MB) L2-resident.
// Wave = 4 row-groups (2 per chunk): 4 independent softmax chains of ILP.
__global__ __launch_bounds__(256, 2) void attn_fwd(const u16* __restrict__ Qd,
                                                   const u16* __restrict__ Kd,
                                                   const u16* __restrict__ Vtd,
                                                   u16* __restrict__ attnb)
{
  __shared__ __align__(16) u16 Kl[2][64*64];
  __shared__ __align__(16) u16 Vl[2][64*64];

  const int t = threadIdx.x;
  const int lane = t & 63, w = t >> 6;
  const int wg = blockIdx.x;
  const int bh = 8 * (wg & 7) + (wg >> 6);   // same bh -> same XCD
  const int p  = (wg >> 3) & 7;
  const int qh = 8 + p, ql = 7 - p;          // complementary pair
  const u16* Qp = Qd  + (size_t)bh * 2048 * 64;
  const u16* Kp = Kd  + (size_t)bh * 2048 * 64;
  const u16* Vp = Vtd + (size_t)bh * 64 * 2048;

  const int fr = lane & 15, g = lane >> 4;
  const int f  = fr & 7;
  const int k8 = g * 8, r4 = g * 4;
  const int qh0 = qh * 128 + w * 32;         // hi-chunk wave base
  const int ql0 = ql * 128 + w * 32;         // lo-chunk wave base
  const int nkt = 2 * qh + 2;

  // Q fragments (global, once). col=q=fr, k = kk*32+k8..+7
  s16x8 qfh[2][2], qfl[2][2];
  #pragma unroll
  for (int rg = 0; rg < 2; rg++)
    #pragma unroll
    for (int kk = 0; kk < 2; kk++){
      qfh[rg][kk] = *(const s16x8*)(Qp + (size_t)(qh0 + rg*16 + fr) * 64 + kk*32 + k8);
      qfl[rg][kk] = *(const s16x8*)(Qp + (size_t)(ql0 + rg*16 + fr) * 64 + kk*32 + k8);
    }

  f32x4 Oh[2][4], Ol[2][4];
  #pragma unroll
  for (int rg = 0; rg < 2; rg++)
    #pragma unroll
    for (int n = 0; n < 4; n++){
      f32x4 z = {0.f,0.f,0.f,0.f}; Oh[rg][n] = z; Ol[rg][n] = z;
    }
  float mh[2] = {-1e30f, -1e30f}, lh[2] = {0.f, 0.f};
  float ml[2] = {-1e30f, -1e30f}, ll[2] = {0.f, 0.f};

  // stage tile 0 (swizzled source, linear LDS dest)
  #pragma unroll
  for (int i = 0; i < 2; i++){
    const int L = i*256 + t;
    const int row = L >> 3, c = L & 7;
    const int cs = c ^ (row & 7);
    gl_lds16(Kp + (size_t)row * 64 + cs*8,   Kl[0] + L*8);
    gl_lds16(Vp + (size_t)row * 2048 + cs*8, Vl[0] + L*8);
  }

  for (int kt = 0; kt < nkt; ++kt){
    __syncthreads();
    const int cur = kt & 1;
    if (kt + 1 < nkt){
      const int kb2 = (kt + 1) * 64;
      u16* Kn = Kl[cur ^ 1]; u16* Vn = Vl[cur ^ 1];
      #pragma unroll
      for (int i = 0; i < 2; i++){
        const int L = i*256 + t;
        const int row = L >> 3, c = L & 7;
        const int cs = c ^ (row & 7);
        gl_lds16(Kp + (size_t)(kb2 + row) * 64 + cs*8, Kn + L*8);
        gl_lds16(Vp + (size_t)row * 2048 + kb2 + cs*8, Vn + L*8);
      }
    }
    const int kb = kt * 64;
    const u16* Kc = Kl[cur];
    const u16* Vc = Vl[cur];

    if (kb <= qh0 + 31)
      chunk_step(Kc, Vc, kb, qh0, qfh, Oh, mh, lh, fr, g, f, r4);
    if (kb <= ql0 + 31)
      chunk_step(Kc, Vc, kb, ql0, qfl, Ol, ml, ll, fr, g, f, r4);
  }

  // ---- epilogue: O^T rows = dk (n*16+r4+r), col = q (fr) ----
  const int b = bh >> 4, h = bh & 15;
  #pragma unroll
  for (int rg = 0; rg < 2; rg++){
    const float invh = 1.0f / lh[rg];
    const float invl = 1.0f / ll[rg];
    const int sh = qh0 + rg*16 + fr;
    const int sl = ql0 + rg*16 + fr;
    #pragma unroll
    for (int n = 0; n < 4; n++){
      u16x4 vh = { f2bf(Oh[rg][n][0]*invh), f2bf(Oh[rg][n][1]*invh),
                   f2bf(Oh[rg][n][2]*invh), f2bf(Oh[rg][n][3]*invh) };
      *(u16x4*)(attnb + (((size_t)b*2048 + sh)*16 + h)*64 + n*16 + r4) = vh;
      u16x4 vl = { f2bf(Ol[rg][n][0]*invl), f2bf(Ol[rg][n][1]*invl),
                   f2bf(Ol[rg][n][2]*invl), f2bf(Ol[rg][n][3]*invl) };
      *(u16x4*)(attnb + (((size_t)b*2048 + sl)*16 + h)*64 + n*16 + r4) = vl;
    }
  }
}

// ---------------- host launch ----------------
extern "C" void kernel_launch(void* const* d_in, const int* in_sizes, int n_in,
                              void* d_out, int out_size, void* d_ws, size_t ws_size,
                              hipStream_t stream)
{
  const float* x    = (const float*)d_in[0];   // (4,2048,1024)
  const float* wqkv = (const float*)d_in[1];   // (3,16,64,1024)
  const float* wo   = (const float*)d_in[2];   // (1024,1024)
  float* out = (float*)d_out;

  char* ws = (char*)d_ws;
  u16* xb    = (u16*)(ws);
  u16* wqb   = (u16*)(ws + 16777216);
  u16* wob   = (u16*)(ws + 23068672);
  u16* Qd    = (u16*)(ws + 25165824);
  u16* Kd    = (u16*)(ws + 41943040);
  u16* Vtd   = (u16*)(ws + 58720256);
  u16* attnb = xb;                               // x dead after gemm_qkv

  cvt_f2b<<<2048, 256, 0, stream>>>(x,    xb,  8388608/4);
  cvt_f2b<<<1024, 256, 0, stream>>>(wqkv, wqb, 3145728/4);
  cvt_f2b<<< 512, 256, 0, stream>>>(wo,   wob, 1048576/4);

  gemm_qkv<<<dim3(64, 24), 256, 0, stream>>>(xb, wqb, Qd, Kd, Vtd);
  attn_fwd<<<dim3(512), 256, 0, stream>>>(Qd, Kd, Vtd, attnb);
  gemm_outp<<<dim3(64, 8), 256, 0, stream>>>(attnb, wob, out);
}

// Round 6
// 211.626 us; speedup vs baseline: 2.6954x; 1.0224x over previous
//
#include <hip/hip_runtime.h>
#include <stdint.h>
#include <stddef.h>

typedef unsigned short u16;
typedef float  f32x4  __attribute__((ext_vector_type(4)));
typedef short  s16x8  __attribute__((ext_vector_type(8)));
typedef short  s16x4  __attribute__((ext_vector_type(4)));
typedef __bf16 bf16x8 __attribute__((ext_vector_type(8)));
typedef __bf16 bf16x4 __attribute__((ext_vector_type(4)));
typedef u16    u16x4  __attribute__((ext_vector_type(4)));

#define DEV static __device__ __forceinline__

DEV u16 f2bf(float f){
  uint32_t u = __builtin_bit_cast(uint32_t, f);
  u += 0x7FFFu + ((u >> 16) & 1u);   // round-to-nearest-even
  return (u16)(u >> 16);
}

DEV f32x4 mfma16(s16x8 a, s16x8 b, f32x4 c){
  return __builtin_amdgcn_mfma_f32_16x16x32_bf16(
      __builtin_bit_cast(bf16x8, a), __builtin_bit_cast(bf16x8, b), c, 0, 0, 0);
}

// K=16 bf16 MFMA: B-frag layout == QK^T D-layout -> PV needs no P re-layout.
DEV f32x4 mfma16k(s16x4 a, s16x4 b, f32x4 c){
  return __builtin_amdgcn_mfma_f32_16x16x16bf16_1k(a, b, c, 0, 0, 0);
}

DEV float exp2_fast(float x){ return __builtin_exp2f(x); }

DEV void gl_lds16(const u16* g, u16* l){
  __builtin_amdgcn_global_load_lds(
      (__attribute__((address_space(1))) void*)(g),
      (__attribute__((address_space(3))) void*)(l), 16, 0, 0);
}

// ---------------- fused fp32 -> bf16 convert (x, w_qkv, w_o) ----------------
// Destinations xb/wqb/wob are contiguous in ws, so one output index works.
__global__ __launch_bounds__(256) void cvt_all(const float* __restrict__ x,
                                               const float* __restrict__ wqkv,
                                               const float* __restrict__ wo,
                                               u16* __restrict__ outb){
  const int N1 = 2097152;            // x float4 count
  const int N2 = N1 + 786432;        // + wqkv
  const int NT = N2 + 262144;        // + wo
  const int stride = gridDim.x * blockDim.x;
  for (int i = blockIdx.x * blockDim.x + threadIdx.x; i < NT; i += stride){
    const float* src; int j;
    if (i < N1){ src = x; j = i; }
    else if (i < N2){ src = wqkv; j = i - N1; }
    else { src = wo; j = i - N2; }
    float4 v = *(const float4*)(src + (size_t)j * 4);
    u16x4 o = { f2bf(v.x), f2bf(v.y), f2bf(v.z), f2bf(v.w) };
    *(u16x4*)(outb + (size_t)i * 4) = o;
  }
}

// ---------------- 128x128 bf16 GEMM core: C = A * Bw^T ----------------
DEV void gemm_core(const u16* __restrict__ A, const u16* __restrict__ Bw,
                   int K, int bm, int bn, u16* ldsA, u16* ldsB, f32x4 acc[4][4])
{
  const int lane = threadIdx.x & 63;
  const int wave = threadIdx.x >> 6;
  const int wm = (wave >> 1) * 64, wn = (wave & 1) * 64;
  const int l8 = (lane & 7) * 8;
  const int lr = lane >> 3;
  const int fr = lane & 15;
  const int k8 = (lane >> 4) * 8;

  #pragma unroll
  for (int m = 0; m < 4; m++)
    #pragma unroll
    for (int n = 0; n < 4; n++){ f32x4 z = {0.f,0.f,0.f,0.f}; acc[m][n] = z; }

  const int nkt = K >> 6;
  for (int kt = 0; kt < nkt; ++kt){
    const int kb = kt * 64;
    #pragma unroll
    for (int i = 0; i < 4; i++){
      const int c   = wave * 4 + i;
      const int row = c * 8 + lr;
      gl_lds16(A  + (size_t)(bm + row) * K + kb + l8, ldsA + c * 512);
      gl_lds16(Bw + (size_t)(bn + row) * K + kb + l8, ldsB + c * 512);
    }
    __syncthreads();
    #pragma unroll
    for (int kk = 0; kk < 2; ++kk){
      s16x8 af[4], bfr[4];
      #pragma unroll
      for (int m = 0; m < 4; m++) af[m]  = *(const s16x8*)(ldsA + (wm + m*16 + fr)*64 + kk*32 + k8);
      #pragma unroll
      for (int n = 0; n < 4; n++) bfr[n] = *(const s16x8*)(ldsB + (wn + n*16 + fr)*64 + kk*32 + k8);
      #pragma unroll
      for (int m = 0; m < 4; m++)
        #pragma unroll
        for (int n = 0; n < 4; n++)
          acc[m][n] = mfma16(af[m], bfr[n], acc[m][n]);
    }
    __syncthreads();
  }
}

// ---------------- QKV projection ----------------
// Q pre-scaled by log2(e)/sqrt(dk) so attention works in exp2 domain.
__global__ __launch_bounds__(256) void gemm_qkv(const u16* __restrict__ xb,
                                                const u16* __restrict__ wb,
                                                u16* __restrict__ Qd,
                                                u16* __restrict__ Kd,
                                                u16* __restrict__ Vtd)
{
  __shared__ __align__(16) u16 ldsA[128*64];
  __shared__ __align__(16) u16 ldsB[128*64];
  f32x4 acc[4][4];
  const int bm = blockIdx.x * 128, bn = blockIdx.y * 128;
  gemm_core(xb, wb, 1024, bm, bn, ldsA, ldsB, acc);

  const int lane = threadIdx.x & 63, wave = threadIdx.x >> 6;
  const int wm = (wave >> 1) * 64, wn = (wave & 1) * 64;
  const int fr = lane & 15, r4 = (lane >> 4) * 4;
  const int q = bn >> 10;

  #pragma unroll
  for (int m = 0; m < 4; m++){
    const int i0 = bm + wm + m*16 + r4;
    const int b  = i0 >> 11;
    const int s0 = i0 & 2047;
    #pragma unroll
    for (int n = 0; n < 4; n++){
      const int ng = bn + wn + n*16 + fr;
      const int h  = (ng >> 6) & 15, kd = ng & 63;
      const size_t bh = (size_t)(b * 16 + h);
      if (q == 0){
        #pragma unroll
        for (int r = 0; r < 4; r++)
          Qd[(bh*2048 + s0 + r)*64 + kd] = f2bf(acc[m][n][r] * 0.18033688011112042f);
      } else if (q == 1){
        #pragma unroll
        for (int r = 0; r < 4; r++)
          Kd[(bh*2048 + s0 + r)*64 + kd] = f2bf(acc[m][n][r]);
      } else {
        u16x4 v = { f2bf(acc[m][n][0]), f2bf(acc[m][n][1]),
                    f2bf(acc[m][n][2]), f2bf(acc[m][n][3]) };
        *(u16x4*)(Vtd + (bh*64 + kd)*2048 + s0) = v;
      }
    }
  }
}

// ---------------- out projection ----------------
__global__ __launch_bounds__(256) void gemm_outp(const u16* __restrict__ attnb,
                                                 const u16* __restrict__ wob,
                                                 float* __restrict__ C)
{
  __shared__ __align__(16) u16 ldsA[128*64];
  __shared__ __align__(16) u16 ldsB[128*64];
  f32x4 acc[4][4];
  const int bm = blockIdx.x * 128, bn = blockIdx.y * 128;
  gemm_core(attnb, wob, 1024, bm, bn, ldsA, ldsB, acc);

  const int lane = threadIdx.x & 63, wave = threadIdx.x >> 6;
  const int wm = (wave >> 1) * 64, wn = (wave & 1) * 64;
  const int fr = lane & 15, r4 = (lane >> 4) * 4;
  #pragma unroll
  for (int m = 0; m < 4; m++){
    const int i0 = bm + wm + m*16 + r4;
    #pragma unroll
    for (int n = 0; n < 4; n++){
      const int ng = bn + wn + n*16 + fr;
      #pragma unroll
      for (int r = 0; r < 4; r++)
        C[(size_t)(i0 + r) * 1024 + ng] = acc[m][n][r];
    }
  }
}

// ---- one 64-key tile for one 32-q chunk-half (2 row groups) ----
// l2[rg] is a PER-LANE PARTIAL sum (this lane's 16 keys); cross-lane reduce
// happens once in the epilogue. Cross-lane max only inside the rare rescale
// branch (defer-max: __all over partial maxima is sufficient to defer).
DEV void chunk_step(const u16* Kc, const u16* Vc, int kb, int q0c,
                    const s16x8 (&qfc)[2][2], f32x4 (&Oc)[2][4],
                    float* m2, float* l2,
                    int fr, int g, int f, int r4)
{
  // QK^T: sc[rg][mi] cols=q(fr), keys mi*16+4g+r
  f32x4 sc[2][4];
  #pragma unroll
  for (int rg = 0; rg < 2; rg++)
    #pragma unroll
    for (int mi = 0; mi < 4; mi++){ f32x4 z = {0.f,0.f,0.f,0.f}; sc[rg][mi] = z; }
  __builtin_amdgcn_s_setprio(1);
  #pragma unroll
  for (int kk = 0; kk < 2; kk++)
    #pragma unroll
    for (int mi = 0; mi < 4; mi++){
      s16x8 kf = *(const s16x8*)(Kc + (mi*16 + fr)*64 + ((kk*4 + g) ^ f)*8);
      sc[0][mi] = mfma16(kf, qfc[0][kk], sc[0][mi]);
      sc[1][mi] = mfma16(kf, qfc[1][kk], sc[1][mi]);
    }
  __builtin_amdgcn_s_setprio(0);

  // online softmax (exp2 domain), P stays in registers
  s16x4 pb[2][4];
  #pragma unroll
  for (int rg = 0; rg < 2; rg++){
    const int q_g = q0c + rg*16 + fr;
    float tmax = -1e30f;
    if (kb + 63 > q0c + rg*16){      // diagonal tile: mask
      #pragma unroll
      for (int mi = 0; mi < 4; mi++)
        #pragma unroll
        for (int r = 0; r < 4; r++){
          const int s_g = kb + mi*16 + r4 + r;
          float v = sc[rg][mi][r];
          v = (s_g > q_g) ? -1e30f : v;
          sc[rg][mi][r] = v;
          tmax = fmaxf(tmax, v);
        }
    } else {
      #pragma unroll
      for (int mi = 0; mi < 4; mi++)
        #pragma unroll
        for (int r = 0; r < 4; r++)
          tmax = fmaxf(tmax, sc[rg][mi][r]);
    }
    float m_new = m2[rg];
    if (!__all(tmax <= m_new + 8.f)){     // T13 defer-max (wave-uniform)
      float tm = fmaxf(tmax, __shfl_xor(tmax, 16));
      tm = fmaxf(tm, __shfl_xor(tm, 32));
      m_new = fmaxf(m_new, tm);
      const float corr = exp2_fast(m2[rg] - m_new);
      m2[rg] = m_new;
      l2[rg] *= corr;                     // corr uniform across the 4 g-lanes
      #pragma unroll
      for (int n = 0; n < 4; n++)
        #pragma unroll
        for (int r = 0; r < 4; r++)
          Oc[rg][n][r] *= corr;           // per-lane scalar (O^T cols=q)
    }
    float tsum = 0.f;
    #pragma unroll
    for (int mi = 0; mi < 4; mi++){
      f32x4 e;
      #pragma unroll
      for (int r = 0; r < 4; r++){
        e[r] = exp2_fast(sc[rg][mi][r] - m_new);
        tsum += e[r];
      }
      pb[rg][mi] = __builtin_bit_cast(s16x4, __builtin_convertvector(e, bf16x4));
    }
    l2[rg] += tsum;                       // per-lane partial, no shuffles
  }

  // PV via 16x16x16 MFMA: O^T[n] += V^T-frag * pb[mi]
  __builtin_amdgcn_s_setprio(1);
  #pragma unroll
  for (int mi = 0; mi < 4; mi++){
    #pragma unroll
    for (int n = 0; n < 4; n++){
      s16x4 vf = *(const s16x4*)(Vc + (n*16 + fr)*64 + ((2*mi + (g >> 1)) ^ f)*8 + (g & 1)*4);
      Oc[0][n] = mfma16k(vf, pb[0][mi], Oc[0][n]);
      Oc[1][n] = mfma16k(vf, pb[1][mi], Oc[1][n]);
    }
  }
  __builtin_amdgcn_s_setprio(0);
}

// ---------------- causal flash attention (v5: paired chunks, shuffle-free) --
__global__ __launch_bounds__(256, 2) void attn_fwd(const u16* __restrict__ Qd,
                                                   const u16* __restrict__ Kd,
                                                   const u16* __restrict__ Vtd,
                                                   u16* __restrict__ attnb)
{
  __shared__ __align__(16) u16 Kl[2][64*64];
  __shared__ __align__(16) u16 Vl[2][64*64];

  const int t = threadIdx.x;
  const int lane = t & 63, w = t >> 6;
  const int wg = blockIdx.x;
  const int bh = 8 * (wg & 7) + (wg >> 6);   // same bh -> same XCD
  const int p  = (wg >> 3) & 7;
  const int qh = 8 + p, ql = 7 - p;          // complementary pair
  const u16* Qp = Qd  + (size_t)bh * 2048 * 64;
  const u16* Kp = Kd  + (size_t)bh * 2048 * 64;
  const u16* Vp = Vtd + (size_t)bh * 64 * 2048;

  const int fr = lane & 15, g = lane >> 4;
  const int f  = fr & 7;
  const int k8 = g * 8, r4 = g * 4;
  const int qh0 = qh * 128 + w * 32;
  const int ql0 = ql * 128 + w * 32;
  const int nkt = 2 * qh + 2;

  s16x8 qfh[2][2], qfl[2][2];
  #pragma unroll
  for (int rg = 0; rg < 2; rg++)
    #pragma unroll
    for (int kk = 0; kk < 2; kk++){
      qfh[rg][kk] = *(const s16x8*)(Qp + (size_t)(qh0 + rg*16 + fr) * 64 + kk*32 + k8);
      qfl[rg][kk] = *(const s16x8*)(Qp + (size_t)(ql0 + rg*16 + fr) * 64 + kk*32 + k8);
    }

  f32x4 Oh[2][4], Ol[2][4];
  #pragma unroll
  for (int rg = 0; rg < 2; rg++)
    #pragma unroll
    for (int n = 0; n < 4; n++){
      f32x4 z = {0.f,0.f,0.f,0.f}; Oh[rg][n] = z; Ol[rg][n] = z;
    }
  float mh[2] = {-1e30f, -1e30f}, lh[2] = {0.f, 0.f};
  float ml[2] = {-1e30f, -1e30f}, ll[2] = {0.f, 0.f};

  // stage tile 0 (swizzled source, linear LDS dest)
  #pragma unroll
  for (int i = 0; i < 2; i++){
    const int L = i*256 + t;
    const int row = L >> 3, c = L & 7;
    const int cs = c ^ (row & 7);
    gl_lds16(Kp + (size_t)row * 64 + cs*8,   Kl[0] + L*8);
    gl_lds16(Vp + (size_t)row * 2048 + cs*8, Vl[0] + L*8);
  }

  for (int kt = 0; kt < nkt; ++kt){
    __syncthreads();
    const int cur = kt & 1;
    if (kt + 1 < nkt){
      const int kb2 = (kt + 1) * 64;
      u16* Kn = Kl[cur ^ 1]; u16* Vn = Vl[cur ^ 1];
      #pragma unroll
      for (int i = 0; i < 2; i++){
        const int L = i*256 + t;
        const int row = L >> 3, c = L & 7;
        const int cs = c ^ (row & 7);
        gl_lds16(Kp + (size_t)(kb2 + row) * 64 + cs*8, Kn + L*8);
        gl_lds16(Vp + (size_t)row * 2048 + kb2 + cs*8, Vn + L*8);
      }
    }
    const int kb = kt * 64;
    const u16* Kc = Kl[cur];
    const u16* Vc = Vl[cur];

    if (kb <= qh0 + 31)
      chunk_step(Kc, Vc, kb, qh0, qfh, Oh, mh, lh, fr, g, f, r4);
    if (kb <= ql0 + 31)
      chunk_step(Kc, Vc, kb, ql0, qfl, Ol, ml, ll, fr, g, f, r4);
  }

  // ---- epilogue: reduce per-lane l partials once, then store ----
  const int b = bh >> 4, h = bh & 15;
  #pragma unroll
  for (int rg = 0; rg < 2; rg++){
    float lsh = lh[rg];
    lsh += __shfl_xor(lsh, 16);
    lsh += __shfl_xor(lsh, 32);
    float lsl = ll[rg];
    lsl += __shfl_xor(lsl, 16);
    lsl += __shfl_xor(lsl, 32);
    const float invh = 1.0f / lsh;
    const float invl = 1.0f / lsl;
    const int sh = qh0 + rg*16 + fr;
    const int sl = ql0 + rg*16 + fr;
    #pragma unroll
    for (int n = 0; n < 4; n++){
      u16x4 vh = { f2bf(Oh[rg][n][0]*invh), f2bf(Oh[rg][n][1]*invh),
                   f2bf(Oh[rg][n][2]*invh), f2bf(Oh[rg][n][3]*invh) };
      *(u16x4*)(attnb + (((size_t)b*2048 + sh)*16 + h)*64 + n*16 + r4) = vh;
      u16x4 vl = { f2bf(Ol[rg][n][0]*invl), f2bf(Ol[rg][n][1]*invl),
                   f2bf(Ol[rg][n][2]*invl), f2bf(Ol[rg][n][3]*invl) };
      *(u16x4*)(attnb + (((size_t)b*2048 + sl)*16 + h)*64 + n*16 + r4) = vl;
    }
  }
}

// ---------------- host launch ----------------
extern "C" void kernel_launch(void* const* d_in, const int* in_sizes, int n_in,
                              void* d_out, int out_size, void* d_ws, size_t ws_size,
                              hipStream_t stream)
{
  const float* x    = (const float*)d_in[0];   // (4,2048,1024)
  const float* wqkv = (const float*)d_in[1];   // (3,16,64,1024)
  const float* wo   = (const float*)d_in[2];   // (1024,1024)
  float* out = (float*)d_out;

  char* ws = (char*)d_ws;
  u16* xb    = (u16*)(ws);                     // xb/wqb/wob contiguous (cvt_all)
  u16* wqb   = (u16*)(ws + 16777216);
  u16* wob   = (u16*)(ws + 23068672);
  u16* Qd    = (u16*)(ws + 25165824);
  u16* Kd    = (u16*)(ws + 41943040);
  u16* Vtd   = (u16*)(ws + 58720256);
  u16* attnb = xb;                             // x dead after gemm_qkv

  cvt_all<<<3072, 256, 0, stream>>>(x, wqkv, wo, xb);
  gemm_qkv<<<dim3(64, 24), 256, 0, stream>>>(xb, wqb, Qd, Kd, Vtd);
  attn_fwd<<<dim3(512), 256, 0, stream>>>(Qd, Kd, Vtd, attnb);
  gemm_outp<<<dim3(64, 8), 256, 0, stream>>>(attnb, wob, out);
}

// Round 7
// 200.279 us; speedup vs baseline: 2.8481x; 1.0567x over previous
//
#include <hip/hip_runtime.h>
#include <stdint.h>
#include <stddef.h>

typedef unsigned short u16;
typedef float  f32x4  __attribute__((ext_vector_type(4)));
typedef short  s16x8  __attribute__((ext_vector_type(8)));
typedef short  s16x4  __attribute__((ext_vector_type(4)));
typedef __bf16 bf16x8 __attribute__((ext_vector_type(8)));
typedef __bf16 bf16x4 __attribute__((ext_vector_type(4)));
typedef u16    u16x4  __attribute__((ext_vector_type(4)));

#define DEV static __device__ __forceinline__

DEV u16 f2bf(float f){
  uint32_t u = __builtin_bit_cast(uint32_t, f);
  u += 0x7FFFu + ((u >> 16) & 1u);   // round-to-nearest-even
  return (u16)(u >> 16);
}

DEV f32x4 mfma16(s16x8 a, s16x8 b, f32x4 c){
  return __builtin_amdgcn_mfma_f32_16x16x32_bf16(
      __builtin_bit_cast(bf16x8, a), __builtin_bit_cast(bf16x8, b), c, 0, 0, 0);
}

// K=16 bf16 MFMA: B-frag layout == QK^T D-layout -> PV needs no P re-layout.
DEV f32x4 mfma16k(s16x4 a, s16x4 b, f32x4 c){
  return __builtin_amdgcn_mfma_f32_16x16x16bf16_1k(a, b, c, 0, 0, 0);
}

DEV float exp2_fast(float x){ return __builtin_exp2f(x); }

DEV void gl_lds16(const u16* g, u16* l){
  __builtin_amdgcn_global_load_lds(
      (__attribute__((address_space(1))) void*)(g),
      (__attribute__((address_space(3))) void*)(l), 16, 0, 0);
}

// ---------------- fused fp32 -> bf16 convert (x, w_qkv, w_o) ----------------
__global__ __launch_bounds__(256) void cvt_all(const float* __restrict__ x,
                                               const float* __restrict__ wqkv,
                                               const float* __restrict__ wo,
                                               u16* __restrict__ outb){
  const int N1 = 2097152;            // x float4 count
  const int N2 = N1 + 786432;        // + wqkv
  const int NT = N2 + 262144;        // + wo
  const int stride = gridDim.x * blockDim.x;
  for (int i = blockIdx.x * blockDim.x + threadIdx.x; i < NT; i += stride){
    const float* src; int j;
    if (i < N1){ src = x; j = i; }
    else if (i < N2){ src = wqkv; j = i - N1; }
    else { src = wo; j = i - N2; }
    float4 v = *(const float4*)(src + (size_t)j * 4);
    u16x4 o = { f2bf(v.x), f2bf(v.y), f2bf(v.z), f2bf(v.w) };
    *(u16x4*)(outb + (size_t)i * 4) = o;
  }
}

// ---------------- 128x128 bf16 GEMM core: C = A * Bw^T ----------------
DEV void gemm_core(const u16* __restrict__ A, const u16* __restrict__ Bw,
                   int K, int bm, int bn, u16* ldsA, u16* ldsB, f32x4 acc[4][4])
{
  const int lane = threadIdx.x & 63;
  const int wave = threadIdx.x >> 6;
  const int wm = (wave >> 1) * 64, wn = (wave & 1) * 64;
  const int l8 = (lane & 7) * 8;
  const int lr = lane >> 3;
  const int fr = lane & 15;
  const int k8 = (lane >> 4) * 8;

  #pragma unroll
  for (int m = 0; m < 4; m++)
    #pragma unroll
    for (int n = 0; n < 4; n++){ f32x4 z = {0.f,0.f,0.f,0.f}; acc[m][n] = z; }

  const int nkt = K >> 6;
  for (int kt = 0; kt < nkt; ++kt){
    const int kb = kt * 64;
    #pragma unroll
    for (int i = 0; i < 4; i++){
      const int c   = wave * 4 + i;
      const int row = c * 8 + lr;
      gl_lds16(A  + (size_t)(bm + row) * K + kb + l8, ldsA + c * 512);
      gl_lds16(Bw + (size_t)(bn + row) * K + kb + l8, ldsB + c * 512);
    }
    __syncthreads();
    #pragma unroll
    for (int kk = 0; kk < 2; ++kk){
      s16x8 af[4], bfr[4];
      #pragma unroll
      for (int m = 0; m < 4; m++) af[m]  = *(const s16x8*)(ldsA + (wm + m*16 + fr)*64 + kk*32 + k8);
      #pragma unroll
      for (int n = 0; n < 4; n++) bfr[n] = *(const s16x8*)(ldsB + (wn + n*16 + fr)*64 + kk*32 + k8);
      #pragma unroll
      for (int m = 0; m < 4; m++)
        #pragma unroll
        for (int n = 0; n < 4; n++)
          acc[m][n] = mfma16(af[m], bfr[n], acc[m][n]);
    }
    __syncthreads();
  }
}

// ---------------- QKV projection ----------------
// Q pre-scaled by log2(e)/sqrt(dk) so attention works in exp2 domain.
__global__ __launch_bounds__(256) void gemm_qkv(const u16* __restrict__ xb,
                                                const u16* __restrict__ wb,
                                                u16* __restrict__ Qd,
                                                u16* __restrict__ Kd,
                                                u16* __restrict__ Vtd)
{
  __shared__ __align__(16) u16 ldsA[128*64];
  __shared__ __align__(16) u16 ldsB[128*64];
  f32x4 acc[4][4];
  const int bm = blockIdx.x * 128, bn = blockIdx.y * 128;
  gemm_core(xb, wb, 1024, bm, bn, ldsA, ldsB, acc);

  const int lane = threadIdx.x & 63, wave = threadIdx.x >> 6;
  const int wm = (wave >> 1) * 64, wn = (wave & 1) * 64;
  const int fr = lane & 15, r4 = (lane >> 4) * 4;
  const int q = bn >> 10;

  #pragma unroll
  for (int m = 0; m < 4; m++){
    const int i0 = bm + wm + m*16 + r4;
    const int b  = i0 >> 11;
    const int s0 = i0 & 2047;
    #pragma unroll
    for (int n = 0; n < 4; n++){
      const int ng = bn + wn + n*16 + fr;
      const int h  = (ng >> 6) & 15, kd = ng & 63;
      const size_t bh = (size_t)(b * 16 + h);
      if (q == 0){
        #pragma unroll
        for (int r = 0; r < 4; r++)
          Qd[(bh*2048 + s0 + r)*64 + kd] = f2bf(acc[m][n][r] * 0.18033688011112042f);
      } else if (q == 1){
        #pragma unroll
        for (int r = 0; r < 4; r++)
          Kd[(bh*2048 + s0 + r)*64 + kd] = f2bf(acc[m][n][r]);
      } else {
        u16x4 v = { f2bf(acc[m][n][0]), f2bf(acc[m][n][1]),
                    f2bf(acc[m][n][2]), f2bf(acc[m][n][3]) };
        *(u16x4*)(Vtd + (bh*64 + kd)*2048 + s0) = v;
      }
    }
  }
}

// ---------------- out projection ----------------
__global__ __launch_bounds__(256) void gemm_outp(const u16* __restrict__ attnb,
                                                 const u16* __restrict__ wob,
                                                 float* __restrict__ C)
{
  __shared__ __align__(16) u16 ldsA[128*64];
  __shared__ __align__(16) u16 ldsB[128*64];
  f32x4 acc[4][4];
  const int bm = blockIdx.x * 128, bn = blockIdx.y * 128;
  gemm_core(attnb, wob, 1024, bm, bn, ldsA, ldsB, acc);

  const int lane = threadIdx.x & 63, wave = threadIdx.x >> 6;
  const int wm = (wave >> 1) * 64, wn = (wave & 1) * 64;
  const int fr = lane & 15, r4 = (lane >> 4) * 4;
  #pragma unroll
  for (int m = 0; m < 4; m++){
    const int i0 = bm + wm + m*16 + r4;
    #pragma unroll
    for (int n = 0; n < 4; n++){
      const int ng = bn + wn + n*16 + fr;
      #pragma unroll
      for (int r = 0; r < 4; r++)
        C[(size_t)(i0 + r) * 1024 + ng] = acc[m][n][r];
    }
  }
}

// ---- one 64-key tile for ONE 16-row q group ----
// L accumulates sum(P) via ones-MFMA (all D-rows equal full key-sum for col q):
// no per-lane partials, no epilogue shuffles. Cross-lane max only inside the
// rare rescale branch (defer-max over per-lane partial maxima).
DEV void chunk_step1(const u16* Kc, const u16* Vc, int kb, int q0,
                     const s16x8 (&qf)[2], f32x4 (&O)[4], f32x4 &L,
                     float &mrun, s16x4 ones,
                     int fr, int g, int f, int r4)
{
  // QK^T: sc[mi] cols=q(fr), keys mi*16+r4+r
  f32x4 sc[4];
  #pragma unroll
  for (int mi = 0; mi < 4; mi++){ f32x4 z = {0.f,0.f,0.f,0.f}; sc[mi] = z; }
  __builtin_amdgcn_s_setprio(1);
  #pragma unroll
  for (int kk = 0; kk < 2; kk++)
    #pragma unroll
    for (int mi = 0; mi < 4; mi++){
      s16x8 kf = *(const s16x8*)(Kc + (mi*16 + fr)*64 + ((kk*4 + g) ^ f)*8);
      sc[mi] = mfma16(kf, qf[kk], sc[mi]);
    }
  __builtin_amdgcn_s_setprio(0);

  const int q_g = q0 + fr;
  float tmax = -1e30f;
  if (kb + 63 > q0){                 // diagonal tile: mask
    #pragma unroll
    for (int mi = 0; mi < 4; mi++)
      #pragma unroll
      for (int r = 0; r < 4; r++){
        const int s_g = kb + mi*16 + r4 + r;
        float v = sc[mi][r];
        v = (s_g > q_g) ? -1e30f : v;
        sc[mi][r] = v;
        tmax = fmaxf(tmax, v);
      }
  } else {
    #pragma unroll
    for (int mi = 0; mi < 4; mi++)
      #pragma unroll
      for (int r = 0; r < 4; r++)
        tmax = fmaxf(tmax, sc[mi][r]);
  }
  float m_new = mrun;
  if (!__all(tmax <= m_new + 8.f)){  // T13 defer-max (wave-uniform)
    float tm = fmaxf(tmax, __shfl_xor(tmax, 16));
    tm = fmaxf(tm, __shfl_xor(tm, 32));
    m_new = fmaxf(m_new, tm);
    const float corr = exp2_fast(mrun - m_new);
    mrun = m_new;
    L[0] *= corr;                    // only row 0 is consumed
    #pragma unroll
    for (int n = 0; n < 4; n++)
      #pragma unroll
      for (int r = 0; r < 4; r++)
        O[n][r] *= corr;             // per-lane scalar (O^T cols=q)
  }
  s16x4 pb[4];
  #pragma unroll
  for (int mi = 0; mi < 4; mi++){
    f32x4 e;
    #pragma unroll
    for (int r = 0; r < 4; r++)
      e[r] = exp2_fast(sc[mi][r] - m_new);
    pb[mi] = __builtin_bit_cast(s16x4, __builtin_convertvector(e, bf16x4));
  }

  // PV + l-sum via 16x16x16 MFMA
  __builtin_amdgcn_s_setprio(1);
  #pragma unroll
  for (int mi = 0; mi < 4; mi++){
    L = mfma16k(ones, pb[mi], L);
    #pragma unroll
    for (int n = 0; n < 4; n++){
      s16x4 vf = *(const s16x4*)(Vc + (n*16 + fr)*64 + ((2*mi + (g >> 1)) ^ f)*8 + (g & 1)*4);
      O[n] = mfma16k(vf, pb[mi], O[n]);
    }
  }
  __builtin_amdgcn_s_setprio(0);
}

// ------- causal flash attention (v6: half-pair blocks, 16 waves/CU) -------
// Grid 1024 flat: (bh 64) x (pair 8) x (half 2). Block = 64 hi + 64 lo q rows;
// wave = 16 hi + 16 lo (rg slot = half*4 + w). 4 blocks/CU co-resident
// (LDS 32 KiB each), 16 waves/CU. XCD decode: 8 bh per XCD, K/V L2-resident.
// Work per block uniform (~2*(qh+ql)+3 tile-steps) -> no causal imbalance.
__global__ __launch_bounds__(256, 4) void attn_fwd(const u16* __restrict__ Qd,
                                                   const u16* __restrict__ Kd,
                                                   const u16* __restrict__ Vtd,
                                                   u16* __restrict__ attnb)
{
  __shared__ __align__(16) u16 Kl[2][64*64];
  __shared__ __align__(16) u16 Vl[2][64*64];

  const int t = threadIdx.x;
  const int lane = t & 63, w = t >> 6;
  const int wg = blockIdx.x;
  const int bh = 8 * (wg & 7) + (wg >> 7);   // same bh -> same XCD
  const int ph = (wg >> 3) & 15;
  const int p  = ph >> 1, half = ph & 1;
  const int qh = 8 + p, ql = 7 - p;          // complementary pair
  const u16* Qp = Qd  + (size_t)bh * 2048 * 64;
  const u16* Kp = Kd  + (size_t)bh * 2048 * 64;
  const u16* Vp = Vtd + (size_t)bh * 64 * 2048;

  const int fr = lane & 15, g = lane >> 4;
  const int f  = fr & 7;
  const int k8 = g * 8, r4 = g * 4;
  const int rgs = half * 4 + w;              // rg slot 0..7 within each chunk
  const int qh0 = qh * 128 + rgs * 16;
  const int ql0 = ql * 128 + rgs * 16;
  const int nkt = 2 * qh + 2;

  const s16x4 ones = { 0x3F80, 0x3F80, 0x3F80, 0x3F80 };   // bf16 1.0

  s16x8 qfh[2], qfl[2];
  #pragma unroll
  for (int kk = 0; kk < 2; kk++){
    qfh[kk] = *(const s16x8*)(Qp + (size_t)(qh0 + fr) * 64 + kk*32 + k8);
    qfl[kk] = *(const s16x8*)(Qp + (size_t)(ql0 + fr) * 64 + kk*32 + k8);
  }

  f32x4 Ohi[4], Olo[4], Lhi, Llo;
  #pragma unroll
  for (int n = 0; n < 4; n++){
    f32x4 z = {0.f,0.f,0.f,0.f}; Ohi[n] = z; Olo[n] = z;
  }
  { f32x4 z = {0.f,0.f,0.f,0.f}; Lhi = z; Llo = z; }
  float mh = -1e30f, ml = -1e30f;

  // staging pointers (swizzled source, linear LDS dest), incremented per tile
  const int Lr  = t >> 3;
  const int cs8 = ((t & 7) ^ (Lr & 7)) * 8;
  const u16* kS = Kp + Lr * 64 + cs8;
  const u16* vS = Vp + (size_t)Lr * 2048 + cs8;

  // stage tile 0 into buffer 0
  gl_lds16(kS,         (u16*)Kl + t*8);
  gl_lds16(kS + 2048,  (u16*)Kl + t*8 + 2048);
  gl_lds16(vS,         (u16*)Vl + t*8);
  gl_lds16(vS + 65536, (u16*)Vl + t*8 + 2048);
  kS += 4096; vS += 64;

  for (int kt = 0; kt < nkt; ++kt){
    __syncthreads();
    const int cur = kt & 1;
    if (kt + 1 < nkt){
      u16* kD = (u16*)Kl + (cur ^ 1) * 4096 + t*8;
      u16* vD = (u16*)Vl + (cur ^ 1) * 4096 + t*8;
      gl_lds16(kS,         kD);
      gl_lds16(kS + 2048,  kD + 2048);
      gl_lds16(vS,         vD);
      gl_lds16(vS + 65536, vD + 2048);
    }
    kS += 4096; vS += 64;

    const int kb = kt * 64;
    const u16* Kc = Kl[cur];
    const u16* Vc = Vl[cur];

    if (kb <= qh0 + 15)
      chunk_step1(Kc, Vc, kb, qh0, qfh, Ohi, Lhi, mh, ones, fr, g, f, r4);
    if (kb <= ql0 + 15)
      chunk_step1(Kc, Vc, kb, ql0, qfl, Olo, Llo, ml, ones, fr, g, f, r4);
  }

  // ---- epilogue: L[0] is the fully-reduced softmax denominator ----
  const int b = bh >> 4, h = bh & 15;
  const float invh = 1.0f / Lhi[0];
  const float invl = 1.0f / Llo[0];
  const int sh = qh0 + fr;
  const int sl = ql0 + fr;
  #pragma unroll
  for (int n = 0; n < 4; n++){
    u16x4 vh = { f2bf(Ohi[n][0]*invh), f2bf(Ohi[n][1]*invh),
                 f2bf(Ohi[n][2]*invh), f2bf(Ohi[n][3]*invh) };
    *(u16x4*)(attnb + (((size_t)b*2048 + sh)*16 + h)*64 + n*16 + r4) = vh;
    u16x4 vl = { f2bf(Olo[n][0]*invl), f2bf(Olo[n][1]*invl),
                 f2bf(Olo[n][2]*invl), f2bf(Olo[n][3]*invl) };
    *(u16x4*)(attnb + (((size_t)b*2048 + sl)*16 + h)*64 + n*16 + r4) = vl;
  }
}

// ---------------- host launch ----------------
extern "C" void kernel_launch(void* const* d_in, const int* in_sizes, int n_in,
                              void* d_out, int out_size, void* d_ws, size_t ws_size,
                              hipStream_t stream)
{
  const float* x    = (const float*)d_in[0];   // (4,2048,1024)
  const float* wqkv = (const float*)d_in[1];   // (3,16,64,1024)
  const float* wo   = (const float*)d_in[2];   // (1024,1024)
  float* out = (float*)d_out;

  char* ws = (char*)d_ws;
  u16* xb    = (u16*)(ws);                     // xb/wqb/wob contiguous (cvt_all)
  u16* wqb   = (u16*)(ws + 16777216);
  u16* wob   = (u16*)(ws + 23068672);
  u16* Qd    = (u16*)(ws + 25165824);
  u16* Kd    = (u16*)(ws + 41943040);
  u16* Vtd   = (u16*)(ws + 58720256);
  u16* attnb = xb;                             // x dead after gemm_qkv

  cvt_all<<<3072, 256, 0, stream>>>(x, wqkv, wo, xb);
  gemm_qkv<<<dim3(64, 24), 256, 0, stream>>>(xb, wqb, Qd, Kd, Vtd);
  attn_fwd<<<dim3(1024), 256, 0, stream>>>(Qd, Kd, Vtd, attnb);
  gemm_outp<<<dim3(64, 8), 256, 0, stream>>>(attnb, wob, out);
}